// Round 20
// baseline (257.486 us; speedup 1.0000x reference)
//
#include <hip/hip_runtime.h>

#define Bn 2
#define Tn 2048
#define Cn 1024
#define NHn 16

typedef __attribute__((ext_vector_type(8))) short s16x8;
typedef __attribute__((ext_vector_type(4))) short s16x4;
typedef __attribute__((ext_vector_type(4))) float f32x4;
typedef __attribute__((ext_vector_type(8))) unsigned short u16x8;
typedef __attribute__((ext_vector_type(4))) unsigned short u16x4;
typedef const __attribute__((address_space(1))) void* gas_t;
typedef __attribute__((address_space(3))) void* las_t;

__device__ __forceinline__ void gl_lds16(const void* g, void* l) {
  __builtin_amdgcn_global_load_lds((gas_t)g, (las_t)l, 16, 0, 0);
}

__device__ __forceinline__ float bf2f(unsigned short u) {
  unsigned int x = ((unsigned int)u) << 16;
  float f; __builtin_memcpy(&f, &x, 4); return f;
}
__device__ __forceinline__ unsigned short f2bf(float f) {
  unsigned int x; __builtin_memcpy(&x, &f, 4);
  x += 0x7fffu + ((x >> 16) & 1u);
  return (unsigned short)(x >> 16);
}
__device__ __forceinline__ unsigned int cvt_pk_bf16(float a, float b) {
  unsigned int r;
  asm("v_cvt_pk_bf16_f32 %0, %1, %2" : "=v"(r) : "v"(a), "v"(b));
  return r;
}
// 16x16x16 bf16 MFMA; __has_builtin check inside the body so the HOST pass
// (where the amdgcn builtin doesn't exist) still parses.
__device__ __forceinline__ f32x4 mfma16_bf16(s16x4 a, s16x4 b, f32x4 c) {
#if defined(__has_builtin)
#if __has_builtin(__builtin_amdgcn_mfma_f32_16x16x16bf16_1k)
  return __builtin_amdgcn_mfma_f32_16x16x16bf16_1k(a, b, c, 0, 0, 0);
#else
  return c;  // host-pass parse only; device pass has the builtin (verified r3/r5)
#endif
#else
  return c;
#endif
}
__device__ __forceinline__ float selu_f(float x) {
  const float SC = 1.0507009873554805f, AL = 1.6732632423543772f;
  return x > 0.f ? SC * x : SC * AL * (__expf(x) - 1.f);
}
__device__ __forceinline__ float waveRS(float v) {
#pragma unroll
  for (int m = 32; m; m >>= 1) v += __shfl_xor(v, m, 64);
  return v;
}

// LDS K-chunk swizzle (rule 21, both-sides): verified BK=32 form (r15) and
// BK=64 form (r16-r18); bank-conflict counter = 0 for both.
template <int BK>
__device__ __forceinline__ int swz_stage(int row, int sl) {
  if constexpr (BK == 32) return sl ^ ((row >> 1) & 3);
  else return sl ^ (row & 7);
}
template <int BK>
__device__ __forceinline__ int swz_read(int rr, int kk, int lg) {
  if constexpr (BK == 32) return lg ^ ((rr >> 1) & 3);
  else return (kk * 4 + lg) ^ (rr & 7);
}

// ---------------- prep: 3 weight casts + modulation in ONE dispatch ----------------
// blocks [0,3072) cast qkv_w; [3072,7168) w1; [7168,11264) w2;
// [11264,12800) modulation (cm = selu(c) @ ada_w.T + ada_b, both batches).
__global__ __launch_bounds__(256) void prep_kernel(
    const float* __restrict__ qkv_w, const float* __restrict__ w1,
    const float* __restrict__ w2, unsigned short* __restrict__ qkvw_bf,
    unsigned short* __restrict__ w1_bf, unsigned short* __restrict__ w2_bf,
    const float* __restrict__ cin, const float* __restrict__ ada_w,
    const float* __restrict__ ada_b, float* __restrict__ cm) {
  const int blk = blockIdx.x;
  const int tid = threadIdx.x;
  if (blk < 11264) {
    const float* in; unsigned short* out; size_t base;
    if (blk < 3072)      { in = qkv_w; out = qkvw_bf; base = (size_t)blk * 1024; }
    else if (blk < 7168) { in = w1;    out = w1_bf;   base = (size_t)(blk - 3072) * 1024; }
    else                 { in = w2;    out = w2_bf;   base = (size_t)(blk - 7168) * 1024; }
    size_t i = base + (size_t)tid * 4;
    float4 v = *(const float4*)(in + i);
    u16x4 o;
    o.x = f2bf(v.x); o.y = f2bf(v.y); o.z = f2bf(v.z); o.w = f2bf(v.w);
    *(u16x4*)(out + i) = o;
  } else {
    const int w = tid >> 6, l = tid & 63;
    const int j = (blk - 11264) * 4 + w;       // 0..6143
    __shared__ float sc[2][1024];
#pragma unroll
    for (int i = 0; i < 4; ++i) {
      int idx = i * 256 + tid;
      sc[0][idx] = selu_f(cin[idx]);
      sc[1][idx] = selu_f(cin[1024 + idx]);
    }
    __syncthreads();
    const float* wr_ = ada_w + (size_t)j * 1024;
    float a0 = 0.f, a1 = 0.f;
#pragma unroll
    for (int i = 0; i < 4; ++i) {
      float4 wv = *(const float4*)(wr_ + (i * 64 + l) * 4);
      const float* s0 = sc[0] + (i * 64 + l) * 4;
      const float* s1 = sc[1] + (i * 64 + l) * 4;
      a0 += wv.x * s0[0] + wv.y * s0[1] + wv.z * s0[2] + wv.w * s0[3];
      a1 += wv.x * s1[0] + wv.y * s1[1] + wv.z * s1[2] + wv.w * s1[3];
    }
    a0 = waveRS(a0);
    a1 = waveRS(a1);
    if (l == 0) {
      const float bb = ada_b[j];
      cm[j] = a0 + bb;
      cm[6144 + j] = a1 + bb;
    }
  }
}

// ---------------- LN + AdaLN modulate -> bf16 ----------------
__global__ __launch_bounds__(256) void ln_mod(
    const float* __restrict__ xin, const float* __restrict__ cm,
    unsigned short* __restrict__ hout, int shift_off, int scale_off) {
  const int tid = threadIdx.x;
  const int row = blockIdx.x;
  const int b = row >> 11;
  const float* xr = xin + (size_t)row * 1024;
  float v[4]; float s = 0.f, s2 = 0.f;
#pragma unroll
  for (int i = 0; i < 4; ++i) {
    v[i] = xr[i * 256 + tid]; s += v[i]; s2 += v[i] * v[i];
  }
  __shared__ float rs[8];
  s = waveRS(s); s2 = waveRS(s2);
  const int w = tid >> 6, l = tid & 63;
  if (l == 0) { rs[w] = s; rs[4 + w] = s2; }
  __syncthreads();
  s = rs[0] + rs[1] + rs[2] + rs[3];
  s2 = rs[4] + rs[5] + rs[6] + rs[7];
  float mean = s * (1.f / 1024.f);
  float var = s2 * (1.f / 1024.f) - mean * mean;
  float rstd = rsqrtf(var + 1e-6f);
  const float* cb = cm + b * 6144;
#pragma unroll
  for (int i = 0; i < 4; ++i) {
    int ch = i * 256 + tid;
    float hv = (v[i] - mean) * rstd * (1.f + cb[scale_off + ch]) + cb[shift_off + ch];
    hout[(size_t)row * 1024 + ch] = f2bf(hv);
  }
}

// ---------------- GEMM: out[M][N] = A[M][K](bf16) * Bw[N][K](bf16)^T ----------------
// MODE 0: +bias -> bf16 ; MODE 1: selu(+bias) -> bf16 ; MODE 2: x2 + gate_f*(+bias) -> f32
// TM: tile rows (128/64). BK: K-step (32/64). 2-phase double-buffer with
// T4 COUNTED vmcnt + raw barriers (r17/r18-verified): no vmcnt(0) drain in
// the loop; prefetch loads stay in flight across barriers.
// Both-sides LDS XOR swizzle; bijective XCD swizzle on flat block index.
template <int MODE, int TM, int BK>
__global__ __launch_bounds__(256) void gemm_bt(
    const unsigned short* __restrict__ A, const unsigned short* __restrict__ Bw,
    const float* __restrict__ bias, unsigned short* __restrict__ obf,
    float* __restrict__ of32, const float* __restrict__ resid,
    const float* __restrict__ cm, int M, int N, int K) {
  constexpr int MR = TM / 32;           // 16-row m-tiles per wave (4 or 2)
  constexpr int CPR = BK / 8;           // 8-elem chunks per row
  constexpr int ACH = TM * BK / 2048;   // A staging chunks per K-step
  constexpr int BCH = 128 * BK / 2048;  // B staging chunks per K-step
  constexpr int KK = BK / 32;           // MFMA K-substeps
  constexpr int LPI = ACH + BCH;        // gl_lds16 issued per stage
  __shared__ unsigned short As[2 * TM * BK];
  __shared__ unsigned short Bs[2 * 128 * BK];
  const int tid = threadIdx.x;
  const int gx = gridDim.x;
  int flat = blockIdx.y * gx + blockIdx.x;
  const int cpx = (gx * gridDim.y) >> 3;   // chunks per XCD
  flat = (flat & 7) * cpx + (flat >> 3);   // XCD-contiguous remap (bijective)
  const int bm = flat / gx, bn = flat % gx;
  const int w = tid >> 6, l = tid & 63;
  const int wr = w >> 1, wc = w & 1;
  const int lr = l & 15, lg = l >> 4;

  f32x4 acc[MR][4];
#pragma unroll
  for (int m = 0; m < MR; ++m)
#pragma unroll
    for (int n = 0; n < 4; ++n) acc[m][n] = (f32x4){0.f, 0.f, 0.f, 0.f};

  const size_t abase = (size_t)bm * TM * K;
  const size_t bbase = (size_t)bn * 128 * K;

#define GEMM_STAGE(KT, HALF)                                                        \
  do {                                                                              \
    const int ko_ = (KT) * BK;                                                      \
    const int hf_ = (HALF);                                                         \
    _Pragma("unroll")                                                               \
    for (int j = 0; j < ACH; ++j) {                                                 \
      const int c = tid + j * 256;                                                  \
      const int row_ = c / CPR, sl_ = c % CPR;                                      \
      const int kcg = swz_stage<BK>(row_, sl_);                                     \
      gl_lds16(A + abase + (size_t)row_ * K + kcg * 8 + ko_,                        \
               As + hf_ * TM * BK + c * 8);                                         \
    }                                                                               \
    _Pragma("unroll")                                                               \
    for (int j = 0; j < BCH; ++j) {                                                 \
      const int c = tid + j * 256;                                                  \
      const int row_ = c / CPR, sl_ = c % CPR;                                      \
      const int kcg = swz_stage<BK>(row_, sl_);                                     \
      gl_lds16(Bw + bbase + (size_t)row_ * K + kcg * 8 + ko_,                       \
               Bs + hf_ * 128 * BK + c * 8);                                        \
    }                                                                               \
  } while (0)

  const int nkt = K / BK;
  GEMM_STAGE(0, 0);
  for (int kt = 0; kt < nkt; ++kt) {
    const int cur = kt & 1;
    if (kt + 1 < nkt) {
      GEMM_STAGE(kt + 1, cur ^ 1);
      // wait for stage(kt)'s LPI loads (issued last iter); stage(kt+1)'s
      // LPI loads remain in flight across the barrier and the MFMAs.
      asm volatile("s_waitcnt vmcnt(%0)" ::"n"(LPI) : "memory");
    } else {
      asm volatile("s_waitcnt vmcnt(0)" ::: "memory");
    }
    __builtin_amdgcn_sched_barrier(0);
    __builtin_amdgcn_s_barrier();  // all waves: buf[cur] fully staged
    __builtin_amdgcn_sched_barrier(0);
    s16x8 af[MR][KK], bf[4][KK];
#pragma unroll
    for (int m = 0; m < MR; ++m) {
      const int rr = wr * (TM / 2) + m * 16 + lr;
#pragma unroll
      for (int kk = 0; kk < KK; ++kk) {
        const int kc = swz_read<BK>(rr, kk, lg);
        af[m][kk] = *(const s16x8*)(As + cur * TM * BK + rr * BK + kc * 8);
      }
    }
#pragma unroll
    for (int n = 0; n < 4; ++n) {
      const int rr = wc * 64 + n * 16 + lr;
#pragma unroll
      for (int kk = 0; kk < KK; ++kk) {
        const int kc = swz_read<BK>(rr, kk, lg);
        bf[n][kk] = *(const s16x8*)(Bs + cur * 128 * BK + rr * BK + kc * 8);
      }
    }
#pragma unroll
    for (int kk = 0; kk < KK; ++kk)
#pragma unroll
      for (int m = 0; m < MR; ++m)
#pragma unroll
        for (int n = 0; n < 4; ++n)
          acc[m][n] = __builtin_amdgcn_mfma_f32_16x16x32_bf16(af[m][kk], bf[n][kk], acc[m][n], 0, 0, 0);
    asm volatile("" ::: "memory");
    __builtin_amdgcn_s_barrier();  // all waves done reading buf[cur]
    __builtin_amdgcn_sched_barrier(0);
  }
#undef GEMM_STAGE

#pragma unroll
  for (int m = 0; m < MR; ++m) {
#pragma unroll
    for (int n = 0; n < 4; ++n) {
      const int col = bn * 128 + wc * 64 + n * 16 + lr;
      const float bv = bias[col];
#pragma unroll
      for (int r = 0; r < 4; ++r) {
        const int row = bm * TM + wr * (TM / 2) + m * 16 + lg * 4 + r;
        float v = acc[m][n][r] + bv;
        if (MODE == 0) {
          obf[(size_t)row * N + col] = f2bf(v);
        } else if (MODE == 1) {
          obf[(size_t)row * N + col] = f2bf(selu_f(v));
        } else {
          const int b = row >> 11;
          const float g = cm[b * 6144 + 5 * 1024 + col];
          of32[(size_t)row * N + col] = resid[(size_t)row * N + col] + g * v;
        }
      }
    }
  }
}

// ---------------- RoPE + repack ----------------
// Q[bh][t][d], K[bh][t][d]; V TILED: Vt[bh][t/16][d/16][16d][16k] so the PV
// A-fragment (lane: d=lr, keys lg*4..+3) reads 512B contiguous per wave.
__global__ __launch_bounds__(256) void rope_pack(
    const unsigned short* __restrict__ qkv, const float* __restrict__ cosp,
    const float* __restrict__ sinp, const float* __restrict__ scalep,
    unsigned short* __restrict__ Qo, unsigned short* __restrict__ Ko,
    unsigned short* __restrict__ Vt) {
  const int tid = threadIdx.x;
  const int blk = blockIdx.x;
  const int tt = blk & 31, bh = blk >> 5;
  const int b = bh >> 4, h = bh & 15;
  const int t0 = tt * 64;
  __shared__ __align__(16) unsigned short tile[64][192];  // [t][q0..63|k64..127|v128..191]
#pragma unroll
  for (int i = 0; i < 6; ++i) {
    int cidx = i * 256 + tid;
    int r = cidx / 24, sg = cidx % 24;
    int colbase = (sg < 8) ? (h * 64 + sg * 8)
                : (sg < 16) ? (Cn + h * 64 + (sg - 8) * 8)
                            : (2 * Cn + h * 64 + (sg - 16) * 8);
    u16x8 v = *(const u16x8*)(qkv + (size_t)(b * Tn + t0 + r) * 3072 + colbase);
    *(u16x8*)(&tile[r][sg * 8]) = v;
  }
  __syncthreads();
  {
    const int t = tid >> 2, d0 = (tid & 3) * 16;
    const int tg = t0 + t;
    float co[16], si[16], sc[16];
#pragma unroll
    for (int i = 0; i < 4; ++i) {
      *(float4*)(co + i * 4) = *(const float4*)(cosp + (size_t)tg * 64 + d0 + i * 4);
      *(float4*)(si + i * 4) = *(const float4*)(sinp + (size_t)tg * 64 + d0 + i * 4);
      *(float4*)(sc + i * 4) = *(const float4*)(scalep + (size_t)tg * 64 + d0 + i * 4);
    }
    u16x8 qv[2], kv[2];
    unsigned short* qo = (unsigned short*)qv;
    unsigned short* ko = (unsigned short*)kv;
#pragma unroll
    for (int i = 0; i < 8; ++i) {
      int d = 2 * i;
      float q0 = bf2f(tile[t][d0 + d]), q1 = bf2f(tile[t][d0 + d + 1]);
      float k0 = bf2f(tile[t][64 + d0 + d]), k1 = bf2f(tile[t][64 + d0 + d + 1]);
      float qr0 = (q0 * co[d] - q1 * si[d]) * sc[d];
      float qr1 = (q1 * co[d + 1] + q0 * si[d + 1]) * sc[d + 1];
      float kr0 = (k0 * co[d] - k1 * si[d]) / sc[d];
      float kr1 = (k1 * co[d + 1] + k0 * si[d + 1]) / sc[d + 1];
      qo[d] = f2bf(qr0); qo[d + 1] = f2bf(qr1);
      ko[d] = f2bf(kr0); ko[d + 1] = f2bf(kr1);
    }
    size_t obase = ((size_t)bh * Tn + tg) * 64 + d0;
    *(u16x8*)(Qo + obase) = qv[0];
    *(u16x8*)(Qo + obase + 8) = qv[1];
    *(u16x8*)(Ko + obase) = kv[0];
    *(u16x8*)(Ko + obase + 8) = kv[1];
  }
  {
    const int d = tid >> 2, ksub = tid & 3;  // d: 0..63, key sub-block: 0..3
    const int kt16 = (t0 >> 4) + ksub;       // global 16-key tile index
    u16x8 vv[2];
    unsigned short* vp = (unsigned short*)vv;
#pragma unroll
    for (int j = 0; j < 16; ++j) vp[j] = tile[ksub * 16 + j][128 + d];
    size_t obase = (((size_t)bh * 128 + kt16) * 4 + (d >> 4)) * 256 + (d & 15) * 16;
    *(u16x8*)(Vt + obase) = vv[0];
    *(u16x8*)(Vt + obase + 8) = vv[1];
  }
}

// ---------------- causal flash attention ----------------
// EXACT r14-r19 kernel (verified passing 6x): swapped QK^T, in-register
// softmax, depth-1 reg pipeline, defer-max THR=8, diagonal-only masking,
// XCD-locality, complement-paired chunks, tiled-V reads. FROZEN.
#define ATTN_LOAD(KB, KF, VF)                                                          \
  do {                                                                                 \
    const int kb_ = (KB);                                                              \
    _Pragma("unroll")                                                                  \
    for (int cc = 0; cc < 2; ++cc) {                                                   \
      const unsigned short* Kp = Kbase + (size_t)(kb_ + cc * 16 + lr) * 64 + lg * 8;   \
      KF[cc][0] = *(const s16x8*)(Kp);                                                 \
      KF[cc][1] = *(const s16x8*)(Kp + 32);                                            \
    }                                                                                  \
    _Pragma("unroll")                                                                  \
    for (int dt = 0; dt < 4; ++dt)                                                     \
      _Pragma("unroll")                                                                \
      for (int cc = 0; cc < 2; ++cc)                                                   \
        VF[dt][cc] = *(const s16x4*)(Vbase + (size_t)(((kb_ >> 4) + cc) * 4 + dt) *    \
                                     256 + lr * 16 + lg * 4);                          \
  } while (0)

#define ATTN_COMP(KB, KF, VF, DOMASK)                                                  \
  do {                                                                                 \
    const int kb_ = (KB);                                                              \
    const bool dm_ = (DOMASK);                                                         \
    f32x4 st[2][2];                                                                    \
    _Pragma("unroll")                                                                  \
    for (int qt = 0; qt < 2; ++qt)                                                     \
      _Pragma("unroll")                                                                \
      for (int cc = 0; cc < 2; ++cc) {                                                 \
        f32x4 t = (f32x4){0.f, 0.f, 0.f, 0.f};                                         \
        t = __builtin_amdgcn_mfma_f32_16x16x32_bf16(KF[cc][0], qa[qt][0], t, 0, 0, 0); \
        t = __builtin_amdgcn_mfma_f32_16x16x32_bf16(KF[cc][1], qa[qt][1], t, 0, 0, 0); \
        st[qt][cc] = t;                                                                \
      }                                                                                \
    _Pragma("unroll")                                                                  \
    for (int qt = 0; qt < 2; ++qt) {                                                   \
      const int q = q0w + qt * 16 + lr;                                                \
      float tmax = -1e30f;                                                             \
      _Pragma("unroll")                                                                \
      for (int cc = 0; cc < 2; ++cc)                                                   \
        _Pragma("unroll")                                                              \
        for (int r = 0; r < 4; ++r) {                                                  \
          float s = st[qt][cc][r] * inv_tp;                                            \
          if (dm_) {                                                                   \
            const int key = kb_ + cc * 16 + lg * 4 + r;                                \
            if (key > q) s = -1e30f;                                                   \
          }                                                                            \
          st[qt][cc][r] = s;                                                           \
          tmax = fmaxf(tmax, s);                                                       \
        }                                                                              \
      tmax = fmaxf(tmax, __shfl_xor(tmax, 16, 64));                                    \
      tmax = fmaxf(tmax, __shfl_xor(tmax, 32, 64));                                    \
      if (__any(tmax > mrow[qt] + 8.f)) {                                              \
        const float mn = fmaxf(mrow[qt], tmax);                                        \
        const float alpha = __expf(mrow[qt] - mn);                                     \
        mrow[qt] = mn;                                                                 \
        lsum[qt] *= alpha;                                                             \
        _Pragma("unroll")                                                              \
        for (int dt = 0; dt < 4; ++dt)                                                 \
          _Pragma("unroll")                                                            \
          for (int r = 0; r < 4; ++r) o[qt][dt][r] *= alpha;                           \
      }                                                                                \
      float p[2][4];                                                                   \
      float part = 0.f;                                                                \
      _Pragma("unroll")                                                                \
      for (int cc = 0; cc < 2; ++cc)                                                   \
        _Pragma("unroll")                                                              \
        for (int r = 0; r < 4; ++r) {                                                  \
          p[cc][r] = __expf(st[qt][cc][r] - mrow[qt]);                                 \
          part += p[cc][r];                                                            \
        }                                                                              \
      part += __shfl_xor(part, 16, 64);                                                \
      part += __shfl_xor(part, 32, 64);                                                \
      lsum[qt] += part;                                                                \
      s16x4 pb[2];                                                                     \
      _Pragma("unroll")                                                                \
      for (int cc = 0; cc < 2; ++cc) {                                                 \
        union { unsigned int u[2]; s16x4 v; } pk;                                      \
        pk.u[0] = cvt_pk_bf16(p[cc][0], p[cc][1]);                                     \
        pk.u[1] = cvt_pk_bf16(p[cc][2], p[cc][3]);                                     \
        pb[cc] = pk.v;                                                                 \
      }                                                                                \
      _Pragma("unroll")                                                                \
      for (int dt = 0; dt < 4; ++dt)                                                   \
        _Pragma("unroll")                                                              \
        for (int cc = 0; cc < 2; ++cc)                                                 \
          o[qt][dt] = mfma16_bf16(VF[dt][cc], pb[cc], o[qt][dt]);                      \
    }                                                                                  \
  } while (0)

__global__ __launch_bounds__(256) void attn_kernel(
    const unsigned short* __restrict__ Q, const unsigned short* __restrict__ Kb,
    const unsigned short* __restrict__ Vt, const float* __restrict__ x,
    const float* __restrict__ cm, float* __restrict__ x2) {
  const int blk = blockIdx.x;
  const int xcd = blk & 7, idx = blk >> 3;
  const int bh = xcd + 8 * (idx & 3);     // 4 heads per XCD
  const int s_ = idx >> 2;                // 0..15 chunk selector
  // complement pairing: co-resident pair (s_, s_+8) gets chunks (15-s_, s_)
  // summing to 15 -> uniform 80 tile-units per CU.
  const int qchunk = (s_ < 8) ? (15 - s_) : (s_ - 8);
  const int b = bh >> 4, h = bh & 15;
  const int tid = threadIdx.x;
  const int w = tid >> 6, l = tid & 63;
  const int lr = l & 15, lg = l >> 4;
  const int q0w = qchunk * 128 + w * 32;  // wave's 32 queries
  const float inv_tp = 0.08838834764831845f;  // 1/sqrt(2*64)

  const unsigned short* Kbase = Kb + (size_t)bh * Tn * 64;
  const unsigned short* Vbase = Vt + (size_t)bh * Tn * 64;  // tiled layout, same size

  // Q fragments (B-operand of swapped QK^T): lane reads Q[q][d-chunk]
  const unsigned short* Qp = Q + ((size_t)bh * Tn + q0w) * 64;
  s16x8 qa[2][2];
#pragma unroll
  for (int qt = 0; qt < 2; ++qt) {
    qa[qt][0] = *(const s16x8*)(Qp + (qt * 16 + lr) * 64 + lg * 8);
    qa[qt][1] = *(const s16x8*)(Qp + (qt * 16 + lr) * 64 + 32 + lg * 8);
  }

  f32x4 o[2][4];  // O^T per q-tile: lane holds d = dt*16+lg*4+r, q = q0w+qt*16+lr
#pragma unroll
  for (int qt = 0; qt < 2; ++qt)
#pragma unroll
    for (int dt = 0; dt < 4; ++dt) o[qt][dt] = (f32x4){0.f, 0.f, 0.f, 0.f};
  float mrow[2] = {-1e30f, -1e30f}, lsum[2] = {0.f, 0.f};

  const int N = (q0w >> 5) + 1;  // tiles; last one is diagonal (masked)
  s16x8 kf0[2][2], kf1[2][2];
  s16x4 vf0[4][2], vf1[4][2];

  ATTN_LOAD(0, kf0, vf0);
  int kt = 0;
  for (; kt + 2 <= N; kt += 2) {
    ATTN_LOAD((kt + 1) * 32, kf1, vf1);
    ATTN_COMP(kt * 32, kf0, vf0, false);        // kt <= N-2: never diagonal
    if (kt + 2 < N) ATTN_LOAD((kt + 2) * 32, kf0, vf0);
    ATTN_COMP((kt + 1) * 32, kf1, vf1, kt + 1 == N - 1);
  }
  if (kt < N) ATTN_COMP(kt * 32, kf0, vf0, true);  // odd N: last tile

  // epilogue: normalize, gate, residual. lane: q = q0w+qt*16+lr, d = dt*16+lg*4+r
#pragma unroll
  for (int qt = 0; qt < 2; ++qt) {
    const float rinv = 1.f / lsum[qt];
    const int q = q0w + qt * 16 + lr;
#pragma unroll
    for (int dt = 0; dt < 4; ++dt) {
      const int colb = h * 64 + dt * 16 + lg * 4;
      const size_t idx2 = ((size_t)b * Tn + q) * Cn + colb;
      float4 xv = *(const float4*)(x + idx2);
      float4 gv = *(const float4*)(cm + b * 6144 + 2048 + colb);
      float4 ov;
      ov.x = xv.x + gv.x * o[qt][dt][0] * rinv;
      ov.y = xv.y + gv.y * o[qt][dt][1] * rinv;
      ov.z = xv.z + gv.z * o[qt][dt][2] * rinv;
      ov.w = xv.w + gv.w * o[qt][dt][3] * rinv;
      *(float4*)(x2 + idx2) = ov;
    }
  }
}

// ---------------- launch ----------------
extern "C" void kernel_launch(void* const* d_in, const int* in_sizes, int n_in,
                              void* d_out, int out_size, void* d_ws, size_t ws_size,
                              hipStream_t stream) {
  (void)in_sizes; (void)n_in; (void)out_size; (void)ws_size;
  const float* x = (const float*)d_in[0];
  const float* pe_cos = (const float*)d_in[1];
  const float* pe_sin = (const float*)d_in[2];
  const float* pe_scale = (const float*)d_in[3];
  const float* cc = (const float*)d_in[4];
  // d_in[5] = mask: causal, computed analytically
  const float* qkv_w = (const float*)d_in[6];
  const float* qkv_b = (const float*)d_in[7];
  const float* w1 = (const float*)d_in[8];
  const float* b1 = (const float*)d_in[9];
  const float* w2 = (const float*)d_in[10];
  const float* b2 = (const float*)d_in[11];
  const float* ada_w = (const float*)d_in[12];
  const float* ada_b = (const float*)d_in[13];
  float* out = (float*)d_out;
  char* ws = (char*)d_ws;

  unsigned short* qkvw_bf = (unsigned short*)(ws + 0);
  unsigned short* w1_bf = (unsigned short*)(ws + 6291456);
  unsigned short* w2_bf = (unsigned short*)(ws + 14680064);
  float* cm = (float*)(ws + 23068672);
  unsigned short* h1 = (unsigned short*)(ws + 23117824);   // reused as h2
  unsigned short* qkvb = (unsigned short*)(ws + 31506432); // reused (+Q) as ff1
  unsigned short* Qb = (unsigned short*)(ws + 56672256);
  unsigned short* Kb2 = (unsigned short*)(ws + 65060864);
  unsigned short* Vtb = (unsigned short*)(ws + 73449472);
  float* x2b = (float*)(ws + 81838080);
  unsigned short* ff1b = (unsigned short*)(ws + 31506432);
  // total ws use: 98,615,296 bytes

  prep_kernel<<<12800, 256, 0, stream>>>(qkv_w, w1, w2, qkvw_bf, w1_bf, w2_bf,
                                         cc, ada_w, ada_b, cm);
  ln_mod<<<4096, 256, 0, stream>>>(x, cm, h1, 0, 1024);
  gemm_bt<0, 64, 32><<<dim3(24, 64), 256, 0, stream>>>(h1, qkvw_bf, qkv_b, qkvb, nullptr, nullptr, nullptr, 4096, 3072, 1024);
  rope_pack<<<1024, 256, 0, stream>>>(qkvb, pe_cos, pe_sin, pe_scale, Qb, Kb2, Vtb);
  attn_kernel<<<512, 256, 0, stream>>>(Qb, Kb2, Vtb, x, cm, x2b);
  ln_mod<<<4096, 256, 0, stream>>>(x2b, cm, h1, 3072, 4096);
  gemm_bt<1, 128, 64><<<dim3(32, 32), 256, 0, stream>>>(h1, w1_bf, b1, ff1b, nullptr, nullptr, nullptr, 4096, 4096, 1024);
  gemm_bt<2, 64, 64><<<dim3(8, 64), 256, 0, stream>>>(ff1b, w2_bf, b2, nullptr, out, x2b, cm, 4096, 1024, 4096);
}

// Round 21
// 241.254 us; speedup vs baseline: 1.0673x; 1.0673x over previous
//
#include <hip/hip_runtime.h>

#define Bn 2
#define Tn 2048
#define Cn 1024
#define NHn 16

typedef __attribute__((ext_vector_type(8))) short s16x8;
typedef __attribute__((ext_vector_type(4))) short s16x4;
typedef __attribute__((ext_vector_type(4))) float f32x4;
typedef __attribute__((ext_vector_type(8))) unsigned short u16x8;
typedef __attribute__((ext_vector_type(4))) unsigned short u16x4;
typedef const __attribute__((address_space(1))) void* gas_t;
typedef __attribute__((address_space(3))) void* las_t;

__device__ __forceinline__ void gl_lds16(const void* g, void* l) {
  __builtin_amdgcn_global_load_lds((gas_t)g, (las_t)l, 16, 0, 0);
}

__device__ __forceinline__ float bf2f(unsigned short u) {
  unsigned int x = ((unsigned int)u) << 16;
  float f; __builtin_memcpy(&f, &x, 4); return f;
}
__device__ __forceinline__ unsigned short f2bf(float f) {
  unsigned int x; __builtin_memcpy(&x, &f, 4);
  x += 0x7fffu + ((x >> 16) & 1u);
  return (unsigned short)(x >> 16);
}
__device__ __forceinline__ unsigned int cvt_pk_bf16(float a, float b) {
  unsigned int r;
  asm("v_cvt_pk_bf16_f32 %0, %1, %2" : "=v"(r) : "v"(a), "v"(b));
  return r;
}
// 16x16x16 bf16 MFMA; __has_builtin check inside the body so the HOST pass
// (where the amdgcn builtin doesn't exist) still parses.
__device__ __forceinline__ f32x4 mfma16_bf16(s16x4 a, s16x4 b, f32x4 c) {
#if defined(__has_builtin)
#if __has_builtin(__builtin_amdgcn_mfma_f32_16x16x16bf16_1k)
  return __builtin_amdgcn_mfma_f32_16x16x16bf16_1k(a, b, c, 0, 0, 0);
#else
  return c;  // host-pass parse only; device pass has the builtin (verified r3/r5)
#endif
#else
  return c;
#endif
}
__device__ __forceinline__ float selu_f(float x) {
  const float SC = 1.0507009873554805f, AL = 1.6732632423543772f;
  return x > 0.f ? SC * x : SC * AL * (__expf(x) - 1.f);
}
__device__ __forceinline__ float waveRS(float v) {
#pragma unroll
  for (int m = 32; m; m >>= 1) v += __shfl_xor(v, m, 64);
  return v;
}

// LDS K-chunk swizzle (rule 21, both-sides): verified BK=32 form (r15) and
// BK=64 form (r16-r18); bank-conflict counter = 0 for both.
template <int BK>
__device__ __forceinline__ int swz_stage(int row, int sl) {
  if constexpr (BK == 32) return sl ^ ((row >> 1) & 3);
  else return sl ^ (row & 7);
}
template <int BK>
__device__ __forceinline__ int swz_read(int rr, int kk, int lg) {
  if constexpr (BK == 32) return lg ^ ((rr >> 1) & 3);
  else return (kk * 4 + lg) ^ (rr & 7);
}

// ---------------- prep: 3 weight casts + modulation in ONE dispatch ----------------
// blocks [0,3072) cast qkv_w; [3072,7168) w1; [7168,11264) w2;
// [11264,12800) modulation (cm = selu(c) @ ada_w.T + ada_b, both batches).
__global__ __launch_bounds__(256) void prep_kernel(
    const float* __restrict__ qkv_w, const float* __restrict__ w1,
    const float* __restrict__ w2, unsigned short* __restrict__ qkvw_bf,
    unsigned short* __restrict__ w1_bf, unsigned short* __restrict__ w2_bf,
    const float* __restrict__ cin, const float* __restrict__ ada_w,
    const float* __restrict__ ada_b, float* __restrict__ cm) {
  const int blk = blockIdx.x;
  const int tid = threadIdx.x;
  if (blk < 11264) {
    const float* in; unsigned short* out; size_t base;
    if (blk < 3072)      { in = qkv_w; out = qkvw_bf; base = (size_t)blk * 1024; }
    else if (blk < 7168) { in = w1;    out = w1_bf;   base = (size_t)(blk - 3072) * 1024; }
    else                 { in = w2;    out = w2_bf;   base = (size_t)(blk - 7168) * 1024; }
    size_t i = base + (size_t)tid * 4;
    float4 v = *(const float4*)(in + i);
    u16x4 o;
    o.x = f2bf(v.x); o.y = f2bf(v.y); o.z = f2bf(v.z); o.w = f2bf(v.w);
    *(u16x4*)(out + i) = o;
  } else {
    const int w = tid >> 6, l = tid & 63;
    const int j = (blk - 11264) * 4 + w;       // 0..6143
    __shared__ float sc[2][1024];
#pragma unroll
    for (int i = 0; i < 4; ++i) {
      int idx = i * 256 + tid;
      sc[0][idx] = selu_f(cin[idx]);
      sc[1][idx] = selu_f(cin[1024 + idx]);
    }
    __syncthreads();
    const float* wr_ = ada_w + (size_t)j * 1024;
    float a0 = 0.f, a1 = 0.f;
#pragma unroll
    for (int i = 0; i < 4; ++i) {
      float4 wv = *(const float4*)(wr_ + (i * 64 + l) * 4);
      const float* s0 = sc[0] + (i * 64 + l) * 4;
      const float* s1 = sc[1] + (i * 64 + l) * 4;
      a0 += wv.x * s0[0] + wv.y * s0[1] + wv.z * s0[2] + wv.w * s0[3];
      a1 += wv.x * s1[0] + wv.y * s1[1] + wv.z * s1[2] + wv.w * s1[3];
    }
    a0 = waveRS(a0);
    a1 = waveRS(a1);
    if (l == 0) {
      const float bb = ada_b[j];
      cm[j] = a0 + bb;
      cm[6144 + j] = a1 + bb;
    }
  }
}

// ---------------- LN + AdaLN modulate -> bf16 ----------------
__global__ __launch_bounds__(256) void ln_mod(
    const float* __restrict__ xin, const float* __restrict__ cm,
    unsigned short* __restrict__ hout, int shift_off, int scale_off) {
  const int tid = threadIdx.x;
  const int row = blockIdx.x;
  const int b = row >> 11;
  const float* xr = xin + (size_t)row * 1024;
  float v[4]; float s = 0.f, s2 = 0.f;
#pragma unroll
  for (int i = 0; i < 4; ++i) {
    v[i] = xr[i * 256 + tid]; s += v[i]; s2 += v[i] * v[i];
  }
  __shared__ float rs[8];
  s = waveRS(s); s2 = waveRS(s2);
  const int w = tid >> 6, l = tid & 63;
  if (l == 0) { rs[w] = s; rs[4 + w] = s2; }
  __syncthreads();
  s = rs[0] + rs[1] + rs[2] + rs[3];
  s2 = rs[4] + rs[5] + rs[6] + rs[7];
  float mean = s * (1.f / 1024.f);
  float var = s2 * (1.f / 1024.f) - mean * mean;
  float rstd = rsqrtf(var + 1e-6f);
  const float* cb = cm + b * 6144;
#pragma unroll
  for (int i = 0; i < 4; ++i) {
    int ch = i * 256 + tid;
    float hv = (v[i] - mean) * rstd * (1.f + cb[scale_off + ch]) + cb[shift_off + ch];
    hout[(size_t)row * 1024 + ch] = f2bf(hv);
  }
}

// ---------------- GEMM: out[M][N] = A[M][K](bf16) * Bw[N][K](bf16)^T ----------------
// MODE 0: +bias -> bf16 ; MODE 1: selu(+bias) -> bf16 ; MODE 2: x2 + gate_f*(+bias) -> f32
// TM: tile rows (128/64). BK: K-step (32/64). 2-phase double-buffer with
// T4 COUNTED vmcnt + raw barriers (r17/r18-verified): no vmcnt(0) drain in
// the loop; prefetch loads stay in flight across barriers.
// Both-sides LDS XOR swizzle; bijective XCD swizzle on flat block index.
// Config sweep result: qkv {128,32} > {128,64} > {64,32}; ffn1/ffn2 best at BK=64.
template <int MODE, int TM, int BK>
__global__ __launch_bounds__(256) void gemm_bt(
    const unsigned short* __restrict__ A, const unsigned short* __restrict__ Bw,
    const float* __restrict__ bias, unsigned short* __restrict__ obf,
    float* __restrict__ of32, const float* __restrict__ resid,
    const float* __restrict__ cm, int M, int N, int K) {
  constexpr int MR = TM / 32;           // 16-row m-tiles per wave (4 or 2)
  constexpr int CPR = BK / 8;           // 8-elem chunks per row
  constexpr int ACH = TM * BK / 2048;   // A staging chunks per K-step
  constexpr int BCH = 128 * BK / 2048;  // B staging chunks per K-step
  constexpr int KK = BK / 32;           // MFMA K-substeps
  constexpr int LPI = ACH + BCH;        // gl_lds16 issued per stage
  __shared__ unsigned short As[2 * TM * BK];
  __shared__ unsigned short Bs[2 * 128 * BK];
  const int tid = threadIdx.x;
  const int gx = gridDim.x;
  int flat = blockIdx.y * gx + blockIdx.x;
  const int cpx = (gx * gridDim.y) >> 3;   // chunks per XCD
  flat = (flat & 7) * cpx + (flat >> 3);   // XCD-contiguous remap (bijective)
  const int bm = flat / gx, bn = flat % gx;
  const int w = tid >> 6, l = tid & 63;
  const int wr = w >> 1, wc = w & 1;
  const int lr = l & 15, lg = l >> 4;

  f32x4 acc[MR][4];
#pragma unroll
  for (int m = 0; m < MR; ++m)
#pragma unroll
    for (int n = 0; n < 4; ++n) acc[m][n] = (f32x4){0.f, 0.f, 0.f, 0.f};

  const size_t abase = (size_t)bm * TM * K;
  const size_t bbase = (size_t)bn * 128 * K;

#define GEMM_STAGE(KT, HALF)                                                        \
  do {                                                                              \
    const int ko_ = (KT) * BK;                                                      \
    const int hf_ = (HALF);                                                         \
    _Pragma("unroll")                                                               \
    for (int j = 0; j < ACH; ++j) {                                                 \
      const int c = tid + j * 256;                                                  \
      const int row_ = c / CPR, sl_ = c % CPR;                                      \
      const int kcg = swz_stage<BK>(row_, sl_);                                     \
      gl_lds16(A + abase + (size_t)row_ * K + kcg * 8 + ko_,                        \
               As + hf_ * TM * BK + c * 8);                                         \
    }                                                                               \
    _Pragma("unroll")                                                               \
    for (int j = 0; j < BCH; ++j) {                                                 \
      const int c = tid + j * 256;                                                  \
      const int row_ = c / CPR, sl_ = c % CPR;                                      \
      const int kcg = swz_stage<BK>(row_, sl_);                                     \
      gl_lds16(Bw + bbase + (size_t)row_ * K + kcg * 8 + ko_,                       \
               Bs + hf_ * 128 * BK + c * 8);                                        \
    }                                                                               \
  } while (0)

  const int nkt = K / BK;
  GEMM_STAGE(0, 0);
  for (int kt = 0; kt < nkt; ++kt) {
    const int cur = kt & 1;
    if (kt + 1 < nkt) {
      GEMM_STAGE(kt + 1, cur ^ 1);
      // wait for stage(kt)'s LPI loads (issued last iter); stage(kt+1)'s
      // LPI loads remain in flight across the barrier and the MFMAs.
      asm volatile("s_waitcnt vmcnt(%0)" ::"n"(LPI) : "memory");
    } else {
      asm volatile("s_waitcnt vmcnt(0)" ::: "memory");
    }
    __builtin_amdgcn_sched_barrier(0);
    __builtin_amdgcn_s_barrier();  // all waves: buf[cur] fully staged
    __builtin_amdgcn_sched_barrier(0);
    s16x8 af[MR][KK], bf[4][KK];
#pragma unroll
    for (int m = 0; m < MR; ++m) {
      const int rr = wr * (TM / 2) + m * 16 + lr;
#pragma unroll
      for (int kk = 0; kk < KK; ++kk) {
        const int kc = swz_read<BK>(rr, kk, lg);
        af[m][kk] = *(const s16x8*)(As + cur * TM * BK + rr * BK + kc * 8);
      }
    }
#pragma unroll
    for (int n = 0; n < 4; ++n) {
      const int rr = wc * 64 + n * 16 + lr;
#pragma unroll
      for (int kk = 0; kk < KK; ++kk) {
        const int kc = swz_read<BK>(rr, kk, lg);
        bf[n][kk] = *(const s16x8*)(Bs + cur * 128 * BK + rr * BK + kc * 8);
      }
    }
#pragma unroll
    for (int kk = 0; kk < KK; ++kk)
#pragma unroll
      for (int m = 0; m < MR; ++m)
#pragma unroll
        for (int n = 0; n < 4; ++n)
          acc[m][n] = __builtin_amdgcn_mfma_f32_16x16x32_bf16(af[m][kk], bf[n][kk], acc[m][n], 0, 0, 0);
    asm volatile("" ::: "memory");
    __builtin_amdgcn_s_barrier();  // all waves done reading buf[cur]
    __builtin_amdgcn_sched_barrier(0);
  }
#undef GEMM_STAGE

#pragma unroll
  for (int m = 0; m < MR; ++m) {
#pragma unroll
    for (int n = 0; n < 4; ++n) {
      const int col = bn * 128 + wc * 64 + n * 16 + lr;
      const float bv = bias[col];
#pragma unroll
      for (int r = 0; r < 4; ++r) {
        const int row = bm * TM + wr * (TM / 2) + m * 16 + lg * 4 + r;
        float v = acc[m][n][r] + bv;
        if (MODE == 0) {
          obf[(size_t)row * N + col] = f2bf(v);
        } else if (MODE == 1) {
          obf[(size_t)row * N + col] = f2bf(selu_f(v));
        } else {
          const int b = row >> 11;
          const float g = cm[b * 6144 + 5 * 1024 + col];
          of32[(size_t)row * N + col] = resid[(size_t)row * N + col] + g * v;
        }
      }
    }
  }
}

// ---------------- RoPE + repack ----------------
// Q[bh][t][d], K[bh][t][d]; V TILED: Vt[bh][t/16][d/16][16d][16k] so the PV
// A-fragment (lane: d=lr, keys lg*4..+3) reads 512B contiguous per wave.
__global__ __launch_bounds__(256) void rope_pack(
    const unsigned short* __restrict__ qkv, const float* __restrict__ cosp,
    const float* __restrict__ sinp, const float* __restrict__ scalep,
    unsigned short* __restrict__ Qo, unsigned short* __restrict__ Ko,
    unsigned short* __restrict__ Vt) {
  const int tid = threadIdx.x;
  const int blk = blockIdx.x;
  const int tt = blk & 31, bh = blk >> 5;
  const int b = bh >> 4, h = bh & 15;
  const int t0 = tt * 64;
  __shared__ __align__(16) unsigned short tile[64][192];  // [t][q0..63|k64..127|v128..191]
#pragma unroll
  for (int i = 0; i < 6; ++i) {
    int cidx = i * 256 + tid;
    int r = cidx / 24, sg = cidx % 24;
    int colbase = (sg < 8) ? (h * 64 + sg * 8)
                : (sg < 16) ? (Cn + h * 64 + (sg - 8) * 8)
                            : (2 * Cn + h * 64 + (sg - 16) * 8);
    u16x8 v = *(const u16x8*)(qkv + (size_t)(b * Tn + t0 + r) * 3072 + colbase);
    *(u16x8*)(&tile[r][sg * 8]) = v;
  }
  __syncthreads();
  {
    const int t = tid >> 2, d0 = (tid & 3) * 16;
    const int tg = t0 + t;
    float co[16], si[16], sc[16];
#pragma unroll
    for (int i = 0; i < 4; ++i) {
      *(float4*)(co + i * 4) = *(const float4*)(cosp + (size_t)tg * 64 + d0 + i * 4);
      *(float4*)(si + i * 4) = *(const float4*)(sinp + (size_t)tg * 64 + d0 + i * 4);
      *(float4*)(sc + i * 4) = *(const float4*)(scalep + (size_t)tg * 64 + d0 + i * 4);
    }
    u16x8 qv[2], kv[2];
    unsigned short* qo = (unsigned short*)qv;
    unsigned short* ko = (unsigned short*)kv;
#pragma unroll
    for (int i = 0; i < 8; ++i) {
      int d = 2 * i;
      float q0 = bf2f(tile[t][d0 + d]), q1 = bf2f(tile[t][d0 + d + 1]);
      float k0 = bf2f(tile[t][64 + d0 + d]), k1 = bf2f(tile[t][64 + d0 + d + 1]);
      float qr0 = (q0 * co[d] - q1 * si[d]) * sc[d];
      float qr1 = (q1 * co[d + 1] + q0 * si[d + 1]) * sc[d + 1];
      float kr0 = (k0 * co[d] - k1 * si[d]) / sc[d];
      float kr1 = (k1 * co[d + 1] + k0 * si[d + 1]) / sc[d + 1];
      qo[d] = f2bf(qr0); qo[d + 1] = f2bf(qr1);
      ko[d] = f2bf(kr0); ko[d + 1] = f2bf(kr1);
    }
    size_t obase = ((size_t)bh * Tn + tg) * 64 + d0;
    *(u16x8*)(Qo + obase) = qv[0];
    *(u16x8*)(Qo + obase + 8) = qv[1];
    *(u16x8*)(Ko + obase) = kv[0];
    *(u16x8*)(Ko + obase + 8) = kv[1];
  }
  {
    const int d = tid >> 2, ksub = tid & 3;  // d: 0..63, key sub-block: 0..3
    const int kt16 = (t0 >> 4) + ksub;       // global 16-key tile index
    u16x8 vv[2];
    unsigned short* vp = (unsigned short*)vv;
#pragma unroll
    for (int j = 0; j < 16; ++j) vp[j] = tile[ksub * 16 + j][128 + d];
    size_t obase = (((size_t)bh * 128 + kt16) * 4 + (d >> 4)) * 256 + (d & 15) * 16;
    *(u16x8*)(Vt + obase) = vv[0];
    *(u16x8*)(Vt + obase + 8) = vv[1];
  }
}

// ---------------- causal flash attention ----------------
// EXACT r14-r20 kernel (verified passing 7x): swapped QK^T, in-register
// softmax, depth-1 reg pipeline, defer-max THR=8, diagonal-only masking,
// XCD-locality, complement-paired chunks, tiled-V reads. FROZEN.
#define ATTN_LOAD(KB, KF, VF)                                                          \
  do {                                                                                 \
    const int kb_ = (KB);                                                              \
    _Pragma("unroll")                                                                  \
    for (int cc = 0; cc < 2; ++cc) {                                                   \
      const unsigned short* Kp = Kbase + (size_t)(kb_ + cc * 16 + lr) * 64 + lg * 8;   \
      KF[cc][0] = *(const s16x8*)(Kp);                                                 \
      KF[cc][1] = *(const s16x8*)(Kp + 32);                                            \
    }                                                                                  \
    _Pragma("unroll")                                                                  \
    for (int dt = 0; dt < 4; ++dt)                                                     \
      _Pragma("unroll")                                                                \
      for (int cc = 0; cc < 2; ++cc)                                                   \
        VF[dt][cc] = *(const s16x4*)(Vbase + (size_t)(((kb_ >> 4) + cc) * 4 + dt) *    \
                                     256 + lr * 16 + lg * 4);                          \
  } while (0)

#define ATTN_COMP(KB, KF, VF, DOMASK)                                                  \
  do {                                                                                 \
    const int kb_ = (KB);                                                              \
    const bool dm_ = (DOMASK);                                                         \
    f32x4 st[2][2];                                                                    \
    _Pragma("unroll")                                                                  \
    for (int qt = 0; qt < 2; ++qt)                                                     \
      _Pragma("unroll")                                                                \
      for (int cc = 0; cc < 2; ++cc) {                                                 \
        f32x4 t = (f32x4){0.f, 0.f, 0.f, 0.f};                                         \
        t = __builtin_amdgcn_mfma_f32_16x16x32_bf16(KF[cc][0], qa[qt][0], t, 0, 0, 0); \
        t = __builtin_amdgcn_mfma_f32_16x16x32_bf16(KF[cc][1], qa[qt][1], t, 0, 0, 0); \
        st[qt][cc] = t;                                                                \
      }                                                                                \
    _Pragma("unroll")                                                                  \
    for (int qt = 0; qt < 2; ++qt) {                                                   \
      const int q = q0w + qt * 16 + lr;                                                \
      float tmax = -1e30f;                                                             \
      _Pragma("unroll")                                                                \
      for (int cc = 0; cc < 2; ++cc)                                                   \
        _Pragma("unroll")                                                              \
        for (int r = 0; r < 4; ++r) {                                                  \
          float s = st[qt][cc][r] * inv_tp;                                            \
          if (dm_) {                                                                   \
            const int key = kb_ + cc * 16 + lg * 4 + r;                                \
            if (key > q) s = -1e30f;                                                   \
          }                                                                            \
          st[qt][cc][r] = s;                                                           \
          tmax = fmaxf(tmax, s);                                                       \
        }                                                                              \
      tmax = fmaxf(tmax, __shfl_xor(tmax, 16, 64));                                    \
      tmax = fmaxf(tmax, __shfl_xor(tmax, 32, 64));                                    \
      if (__any(tmax > mrow[qt] + 8.f)) {                                              \
        const float mn = fmaxf(mrow[qt], tmax);                                        \
        const float alpha = __expf(mrow[qt] - mn);                                     \
        mrow[qt] = mn;                                                                 \
        lsum[qt] *= alpha;                                                             \
        _Pragma("unroll")                                                              \
        for (int dt = 0; dt < 4; ++dt)                                                 \
          _Pragma("unroll")                                                            \
          for (int r = 0; r < 4; ++r) o[qt][dt][r] *= alpha;                           \
      }                                                                                \
      float p[2][4];                                                                   \
      float part = 0.f;                                                                \
      _Pragma("unroll")                                                                \
      for (int cc = 0; cc < 2; ++cc)                                                   \
        _Pragma("unroll")                                                              \
        for (int r = 0; r < 4; ++r) {                                                  \
          p[cc][r] = __expf(st[qt][cc][r] - mrow[qt]);                                 \
          part += p[cc][r];                                                            \
        }                                                                              \
      part += __shfl_xor(part, 16, 64);                                                \
      part += __shfl_xor(part, 32, 64);                                                \
      lsum[qt] += part;                                                                \
      s16x4 pb[2];                                                                     \
      _Pragma("unroll")                                                                \
      for (int cc = 0; cc < 2; ++cc) {                                                 \
        union { unsigned int u[2]; s16x4 v; } pk;                                      \
        pk.u[0] = cvt_pk_bf16(p[cc][0], p[cc][1]);                                     \
        pk.u[1] = cvt_pk_bf16(p[cc][2], p[cc][3]);                                     \
        pb[cc] = pk.v;                                                                 \
      }                                                                                \
      _Pragma("unroll")                                                                \
      for (int dt = 0; dt < 4; ++dt)                                                   \
        _Pragma("unroll")                                                              \
        for (int cc = 0; cc < 2; ++cc)                                                 \
          o[qt][dt] = mfma16_bf16(VF[dt][cc], pb[cc], o[qt][dt]);                      \
    }                                                                                  \
  } while (0)

__global__ __launch_bounds__(256) void attn_kernel(
    const unsigned short* __restrict__ Q, const unsigned short* __restrict__ Kb,
    const unsigned short* __restrict__ Vt, const float* __restrict__ x,
    const float* __restrict__ cm, float* __restrict__ x2) {
  const int blk = blockIdx.x;
  const int xcd = blk & 7, idx = blk >> 3;
  const int bh = xcd + 8 * (idx & 3);     // 4 heads per XCD
  const int s_ = idx >> 2;                // 0..15 chunk selector
  // complement pairing: co-resident pair (s_, s_+8) gets chunks (15-s_, s_)
  // summing to 15 -> uniform 80 tile-units per CU.
  const int qchunk = (s_ < 8) ? (15 - s_) : (s_ - 8);
  const int b = bh >> 4, h = bh & 15;
  const int tid = threadIdx.x;
  const int w = tid >> 6, l = tid & 63;
  const int lr = l & 15, lg = l >> 4;
  const int q0w = qchunk * 128 + w * 32;  // wave's 32 queries
  const float inv_tp = 0.08838834764831845f;  // 1/sqrt(2*64)

  const unsigned short* Kbase = Kb + (size_t)bh * Tn * 64;
  const unsigned short* Vbase = Vt + (size_t)bh * Tn * 64;  // tiled layout, same size

  // Q fragments (B-operand of swapped QK^T): lane reads Q[q][d-chunk]
  const unsigned short* Qp = Q + ((size_t)bh * Tn + q0w) * 64;
  s16x8 qa[2][2];
#pragma unroll
  for (int qt = 0; qt < 2; ++qt) {
    qa[qt][0] = *(const s16x8*)(Qp + (qt * 16 + lr) * 64 + lg * 8);
    qa[qt][1] = *(const s16x8*)(Qp + (qt * 16 + lr) * 64 + 32 + lg * 8);
  }

  f32x4 o[2][4];  // O^T per q-tile: lane holds d = dt*16+lg*4+r, q = q0w+qt*16+lr
#pragma unroll
  for (int qt = 0; qt < 2; ++qt)
#pragma unroll
    for (int dt = 0; dt < 4; ++dt) o[qt][dt] = (f32x4){0.f, 0.f, 0.f, 0.f};
  float mrow[2] = {-1e30f, -1e30f}, lsum[2] = {0.f, 0.f};

  const int N = (q0w >> 5) + 1;  // tiles; last one is diagonal (masked)
  s16x8 kf0[2][2], kf1[2][2];
  s16x4 vf0[4][2], vf1[4][2];

  ATTN_LOAD(0, kf0, vf0);
  int kt = 0;
  for (; kt + 2 <= N; kt += 2) {
    ATTN_LOAD((kt + 1) * 32, kf1, vf1);
    ATTN_COMP(kt * 32, kf0, vf0, false);        // kt <= N-2: never diagonal
    if (kt + 2 < N) ATTN_LOAD((kt + 2) * 32, kf0, vf0);
    ATTN_COMP((kt + 1) * 32, kf1, vf1, kt + 1 == N - 1);
  }
  if (kt < N) ATTN_COMP(kt * 32, kf0, vf0, true);  // odd N: last tile

  // epilogue: normalize, gate, residual. lane: q = q0w+qt*16+lr, d = dt*16+lg*4+r
#pragma unroll
  for (int qt = 0; qt < 2; ++qt) {
    const float rinv = 1.f / lsum[qt];
    const int q = q0w + qt * 16 + lr;
#pragma unroll
    for (int dt = 0; dt < 4; ++dt) {
      const int colb = h * 64 + dt * 16 + lg * 4;
      const size_t idx2 = ((size_t)b * Tn + q) * Cn + colb;
      float4 xv = *(const float4*)(x + idx2);
      float4 gv = *(const float4*)(cm + b * 6144 + 2048 + colb);
      float4 ov;
      ov.x = xv.x + gv.x * o[qt][dt][0] * rinv;
      ov.y = xv.y + gv.y * o[qt][dt][1] * rinv;
      ov.z = xv.z + gv.z * o[qt][dt][2] * rinv;
      ov.w = xv.w + gv.w * o[qt][dt][3] * rinv;
      *(float4*)(x2 + idx2) = ov;
    }
  }
}

// ---------------- launch ----------------
extern "C" void kernel_launch(void* const* d_in, const int* in_sizes, int n_in,
                              void* d_out, int out_size, void* d_ws, size_t ws_size,
                              hipStream_t stream) {
  (void)in_sizes; (void)n_in; (void)out_size; (void)ws_size;
  const float* x = (const float*)d_in[0];
  const float* pe_cos = (const float*)d_in[1];
  const float* pe_sin = (const float*)d_in[2];
  const float* pe_scale = (const float*)d_in[3];
  const float* cc = (const float*)d_in[4];
  // d_in[5] = mask: causal, computed analytically
  const float* qkv_w = (const float*)d_in[6];
  const float* qkv_b = (const float*)d_in[7];
  const float* w1 = (const float*)d_in[8];
  const float* b1 = (const float*)d_in[9];
  const float* w2 = (const float*)d_in[10];
  const float* b2 = (const float*)d_in[11];
  const float* ada_w = (const float*)d_in[12];
  const float* ada_b = (const float*)d_in[13];
  float* out = (float*)d_out;
  char* ws = (char*)d_ws;

  unsigned short* qkvw_bf = (unsigned short*)(ws + 0);
  unsigned short* w1_bf = (unsigned short*)(ws + 6291456);
  unsigned short* w2_bf = (unsigned short*)(ws + 14680064);
  float* cm = (float*)(ws + 23068672);
  unsigned short* h1 = (unsigned short*)(ws + 23117824);   // reused as h2
  unsigned short* qkvb = (unsigned short*)(ws + 31506432); // reused (+Q) as ff1
  unsigned short* Qb = (unsigned short*)(ws + 56672256);
  unsigned short* Kb2 = (unsigned short*)(ws + 65060864);
  unsigned short* Vtb = (unsigned short*)(ws + 73449472);
  float* x2b = (float*)(ws + 81838080);
  unsigned short* ff1b = (unsigned short*)(ws + 31506432);
  // total ws use: 98,615,296 bytes

  prep_kernel<<<12800, 256, 0, stream>>>(qkv_w, w1, w2, qkvw_bf, w1_bf, w2_bf,
                                         cc, ada_w, ada_b, cm);
  ln_mod<<<4096, 256, 0, stream>>>(x, cm, h1, 0, 1024);
  gemm_bt<0, 128, 32><<<dim3(24, 32), 256, 0, stream>>>(h1, qkvw_bf, qkv_b, qkvb, nullptr, nullptr, nullptr, 4096, 3072, 1024);
  rope_pack<<<1024, 256, 0, stream>>>(qkvb, pe_cos, pe_sin, pe_scale, Qb, Kb2, Vtb);
  attn_kernel<<<512, 256, 0, stream>>>(Qb, Kb2, Vtb, x, cm, x2b);
  ln_mod<<<4096, 256, 0, stream>>>(x2b, cm, h1, 3072, 4096);
  gemm_bt<1, 128, 64><<<dim3(32, 32), 256, 0, stream>>>(h1, w1_bf, b1, ff1b, nullptr, nullptr, nullptr, 4096, 4096, 1024);
  gemm_bt<2, 64, 64><<<dim3(8, 64), 256, 0, stream>>>(ff1b, w2_bf, b2, nullptr, out, x2b, cm, 4096, 1024, 4096);
}

// Round 22
// 239.283 us; speedup vs baseline: 1.0761x; 1.0082x over previous
//
#include <hip/hip_runtime.h>

#define Bn 2
#define Tn 2048
#define Cn 1024
#define NHn 16

typedef __attribute__((ext_vector_type(8))) short s16x8;
typedef __attribute__((ext_vector_type(4))) short s16x4;
typedef __attribute__((ext_vector_type(4))) float f32x4;
typedef __attribute__((ext_vector_type(8))) unsigned short u16x8;
typedef __attribute__((ext_vector_type(4))) unsigned short u16x4;
typedef const __attribute__((address_space(1))) void* gas_t;
typedef __attribute__((address_space(3))) void* las_t;

__device__ __forceinline__ void gl_lds16(const void* g, void* l) {
  __builtin_amdgcn_global_load_lds((gas_t)g, (las_t)l, 16, 0, 0);
}

__device__ __forceinline__ float bf2f(unsigned short u) {
  unsigned int x = ((unsigned int)u) << 16;
  float f; __builtin_memcpy(&f, &x, 4); return f;
}
__device__ __forceinline__ unsigned short f2bf(float f) {
  unsigned int x; __builtin_memcpy(&x, &f, 4);
  x += 0x7fffu + ((x >> 16) & 1u);
  return (unsigned short)(x >> 16);
}
__device__ __forceinline__ unsigned int cvt_pk_bf16(float a, float b) {
  unsigned int r;
  asm("v_cvt_pk_bf16_f32 %0, %1, %2" : "=v"(r) : "v"(a), "v"(b));
  return r;
}
// 16x16x16 bf16 MFMA; __has_builtin check inside the body so the HOST pass
// (where the amdgcn builtin doesn't exist) still parses.
__device__ __forceinline__ f32x4 mfma16_bf16(s16x4 a, s16x4 b, f32x4 c) {
#if defined(__has_builtin)
#if __has_builtin(__builtin_amdgcn_mfma_f32_16x16x16bf16_1k)
  return __builtin_amdgcn_mfma_f32_16x16x16bf16_1k(a, b, c, 0, 0, 0);
#else
  return c;  // host-pass parse only; device pass has the builtin (verified r3/r5)
#endif
#else
  return c;
#endif
}
__device__ __forceinline__ float selu_f(float x) {
  const float SC = 1.0507009873554805f, AL = 1.6732632423543772f;
  return x > 0.f ? SC * x : SC * AL * (__expf(x) - 1.f);
}
__device__ __forceinline__ float waveRS(float v) {
#pragma unroll
  for (int m = 32; m; m >>= 1) v += __shfl_xor(v, m, 64);
  return v;
}

// LDS K-chunk swizzle (rule 21, both-sides): verified BK=32 form (r15) and
// BK=64 form (r16-r18); bank-conflict counter = 0 for both.
template <int BK>
__device__ __forceinline__ int swz_stage(int row, int sl) {
  if constexpr (BK == 32) return sl ^ ((row >> 1) & 3);
  else return sl ^ (row & 7);
}
template <int BK>
__device__ __forceinline__ int swz_read(int rr, int kk, int lg) {
  if constexpr (BK == 32) return lg ^ ((rr >> 1) & 3);
  else return (kk * 4 + lg) ^ (rr & 7);
}

// ---------------- prep: 3 weight casts + modulation in ONE dispatch ----------------
__global__ __launch_bounds__(256) void prep_kernel(
    const float* __restrict__ qkv_w, const float* __restrict__ w1,
    const float* __restrict__ w2, unsigned short* __restrict__ qkvw_bf,
    unsigned short* __restrict__ w1_bf, unsigned short* __restrict__ w2_bf,
    const float* __restrict__ cin, const float* __restrict__ ada_w,
    const float* __restrict__ ada_b, float* __restrict__ cm) {
  const int blk = blockIdx.x;
  const int tid = threadIdx.x;
  if (blk < 11264) {
    const float* in; unsigned short* out; size_t base;
    if (blk < 3072)      { in = qkv_w; out = qkvw_bf; base = (size_t)blk * 1024; }
    else if (blk < 7168) { in = w1;    out = w1_bf;   base = (size_t)(blk - 3072) * 1024; }
    else                 { in = w2;    out = w2_bf;   base = (size_t)(blk - 7168) * 1024; }
    size_t i = base + (size_t)tid * 4;
    float4 v = *(const float4*)(in + i);
    u16x4 o;
    o.x = f2bf(v.x); o.y = f2bf(v.y); o.z = f2bf(v.z); o.w = f2bf(v.w);
    *(u16x4*)(out + i) = o;
  } else {
    const int w = tid >> 6, l = tid & 63;
    const int j = (blk - 11264) * 4 + w;       // 0..6143
    __shared__ float sc[2][1024];
#pragma unroll
    for (int i = 0; i < 4; ++i) {
      int idx = i * 256 + tid;
      sc[0][idx] = selu_f(cin[idx]);
      sc[1][idx] = selu_f(cin[1024 + idx]);
    }
    __syncthreads();
    const float* wr_ = ada_w + (size_t)j * 1024;
    float a0 = 0.f, a1 = 0.f;
#pragma unroll
    for (int i = 0; i < 4; ++i) {
      float4 wv = *(const float4*)(wr_ + (i * 64 + l) * 4);
      const float* s0 = sc[0] + (i * 64 + l) * 4;
      const float* s1 = sc[1] + (i * 64 + l) * 4;
      a0 += wv.x * s0[0] + wv.y * s0[1] + wv.z * s0[2] + wv.w * s0[3];
      a1 += wv.x * s1[0] + wv.y * s1[1] + wv.z * s1[2] + wv.w * s1[3];
    }
    a0 = waveRS(a0);
    a1 = waveRS(a1);
    if (l == 0) {
      const float bb = ada_b[j];
      cm[j] = a0 + bb;
      cm[6144 + j] = a1 + bb;
    }
  }
}

// ---------------- LN + AdaLN modulate -> bf16 ----------------
__global__ __launch_bounds__(256) void ln_mod(
    const float* __restrict__ xin, const float* __restrict__ cm,
    unsigned short* __restrict__ hout, int shift_off, int scale_off) {
  const int tid = threadIdx.x;
  const int row = blockIdx.x;
  const int b = row >> 11;
  const float* xr = xin + (size_t)row * 1024;
  float v[4]; float s = 0.f, s2 = 0.f;
#pragma unroll
  for (int i = 0; i < 4; ++i) {
    v[i] = xr[i * 256 + tid]; s += v[i]; s2 += v[i] * v[i];
  }
  __shared__ float rs[8];
  s = waveRS(s); s2 = waveRS(s2);
  const int w = tid >> 6, l = tid & 63;
  if (l == 0) { rs[w] = s; rs[4 + w] = s2; }
  __syncthreads();
  s = rs[0] + rs[1] + rs[2] + rs[3];
  s2 = rs[4] + rs[5] + rs[6] + rs[7];
  float mean = s * (1.f / 1024.f);
  float var = s2 * (1.f / 1024.f) - mean * mean;
  float rstd = rsqrtf(var + 1e-6f);
  const float* cb = cm + b * 6144;
#pragma unroll
  for (int i = 0; i < 4; ++i) {
    int ch = i * 256 + tid;
    float hv = (v[i] - mean) * rstd * (1.f + cb[scale_off + ch]) + cb[shift_off + ch];
    hout[(size_t)row * 1024 + ch] = f2bf(hv);
  }
}

// ---------------- GEMM: out[M][N] = A[M][K](bf16) * Bw[N][K](bf16)^T ----------------
// MODE 0: +bias -> bf16 ; MODE 1: selu(+bias) -> bf16 ; MODE 2: x2 + gate_f*(+bias) -> f32
// MODE 3: qkv fused epilogue: +bias, RoPE(Q,K) with pe tables, scatter to
//   Q[bh][t][d], K[bh][t][d], tiled Vt (layout formulas identical to the
//   verified rope_pack writer / ATTN_LOAD reader pair).
// TM: tile rows (128/64). BK: K-step (32/64). 2-phase double-buffer with
// T4 COUNTED vmcnt + raw barriers; both-sides LDS XOR swizzle; XCD swizzle.
template <int MODE, int TM, int BK>
__global__ __launch_bounds__(256) void gemm_bt(
    const unsigned short* __restrict__ A, const unsigned short* __restrict__ Bw,
    const float* __restrict__ bias, unsigned short* __restrict__ obf,
    float* __restrict__ of32, const float* __restrict__ resid,
    const float* __restrict__ cm, int M, int N, int K,
    const float* __restrict__ pe_c, const float* __restrict__ pe_s,
    const float* __restrict__ pe_sc, unsigned short* __restrict__ q_out,
    unsigned short* __restrict__ k_out, unsigned short* __restrict__ v_out) {
  constexpr int MR = TM / 32;           // 16-row m-tiles per wave (4 or 2)
  constexpr int CPR = BK / 8;           // 8-elem chunks per row
  constexpr int ACH = TM * BK / 2048;   // A staging chunks per K-step
  constexpr int BCH = 128 * BK / 2048;  // B staging chunks per K-step
  constexpr int KK = BK / 32;           // MFMA K-substeps
  constexpr int LPI = ACH + BCH;        // gl_lds16 issued per stage
  __shared__ unsigned short As[2 * TM * BK];
  __shared__ unsigned short Bs[2 * 128 * BK];
  const int tid = threadIdx.x;
  const int gx = gridDim.x;
  int flat = blockIdx.y * gx + blockIdx.x;
  const int cpx = (gx * gridDim.y) >> 3;   // chunks per XCD
  flat = (flat & 7) * cpx + (flat >> 3);   // XCD-contiguous remap (bijective)
  const int bm = flat / gx, bn = flat % gx;
  const int w = tid >> 6, l = tid & 63;
  const int wr = w >> 1, wc = w & 1;
  const int lr = l & 15, lg = l >> 4;

  f32x4 acc[MR][4];
#pragma unroll
  for (int m = 0; m < MR; ++m)
#pragma unroll
    for (int n = 0; n < 4; ++n) acc[m][n] = (f32x4){0.f, 0.f, 0.f, 0.f};

  const size_t abase = (size_t)bm * TM * K;
  const size_t bbase = (size_t)bn * 128 * K;

#define GEMM_STAGE(KT, HALF)                                                        \
  do {                                                                              \
    const int ko_ = (KT) * BK;                                                      \
    const int hf_ = (HALF);                                                         \
    _Pragma("unroll")                                                               \
    for (int j = 0; j < ACH; ++j) {                                                 \
      const int c = tid + j * 256;                                                  \
      const int row_ = c / CPR, sl_ = c % CPR;                                      \
      const int kcg = swz_stage<BK>(row_, sl_);                                     \
      gl_lds16(A + abase + (size_t)row_ * K + kcg * 8 + ko_,                        \
               As + hf_ * TM * BK + c * 8);                                         \
    }                                                                               \
    _Pragma("unroll")                                                               \
    for (int j = 0; j < BCH; ++j) {                                                 \
      const int c = tid + j * 256;                                                  \
      const int row_ = c / CPR, sl_ = c % CPR;                                      \
      const int kcg = swz_stage<BK>(row_, sl_);                                     \
      gl_lds16(Bw + bbase + (size_t)row_ * K + kcg * 8 + ko_,                       \
               Bs + hf_ * 128 * BK + c * 8);                                        \
    }                                                                               \
  } while (0)

  const int nkt = K / BK;
  GEMM_STAGE(0, 0);
  for (int kt = 0; kt < nkt; ++kt) {
    const int cur = kt & 1;
    if (kt + 1 < nkt) {
      GEMM_STAGE(kt + 1, cur ^ 1);
      asm volatile("s_waitcnt vmcnt(%0)" ::"n"(LPI) : "memory");
    } else {
      asm volatile("s_waitcnt vmcnt(0)" ::: "memory");
    }
    __builtin_amdgcn_sched_barrier(0);
    __builtin_amdgcn_s_barrier();  // all waves: buf[cur] fully staged
    __builtin_amdgcn_sched_barrier(0);
    s16x8 af[MR][KK], bf[4][KK];
#pragma unroll
    for (int m = 0; m < MR; ++m) {
      const int rr = wr * (TM / 2) + m * 16 + lr;
#pragma unroll
      for (int kk = 0; kk < KK; ++kk) {
        const int kc = swz_read<BK>(rr, kk, lg);
        af[m][kk] = *(const s16x8*)(As + cur * TM * BK + rr * BK + kc * 8);
      }
    }
#pragma unroll
    for (int n = 0; n < 4; ++n) {
      const int rr = wc * 64 + n * 16 + lr;
#pragma unroll
      for (int kk = 0; kk < KK; ++kk) {
        const int kc = swz_read<BK>(rr, kk, lg);
        bf[n][kk] = *(const s16x8*)(Bs + cur * 128 * BK + rr * BK + kc * 8);
      }
    }
#pragma unroll
    for (int kk = 0; kk < KK; ++kk)
#pragma unroll
      for (int m = 0; m < MR; ++m)
#pragma unroll
        for (int n = 0; n < 4; ++n)
          acc[m][n] = __builtin_amdgcn_mfma_f32_16x16x32_bf16(af[m][kk], bf[n][kk], acc[m][n], 0, 0, 0);
    asm volatile("" ::: "memory");
    __builtin_amdgcn_s_barrier();  // all waves done reading buf[cur]
    __builtin_amdgcn_sched_barrier(0);
  }
#undef GEMM_STAGE

#pragma unroll
  for (int m = 0; m < MR; ++m) {
#pragma unroll
    for (int n = 0; n < 4; ++n) {
      const int col = bn * 128 + wc * 64 + n * 16 + lr;
      const float bv = bias[col];
      if (MODE == 3) {
        // wave-uniform per (m,n): section / head (16-col span never crosses
        // a 64-boundary); d parity == lr parity, RoPE pair lives in lane lr^1.
        const int row0 = bm * TM + wr * (TM / 2) + m * 16 + lg * 4;
        const int sec = col >> 10;           // 0=Q 1=K 2=V
        const int cc2 = col & 1023;
        const int hh = cc2 >> 6, dd = cc2 & 63;
        const int bb = row0 >> 11;
        const int tt0 = row0 & 2047;
        const int bh = bb * 16 + hh;
        float vv[4];
#pragma unroll
        for (int r = 0; r < 4; ++r) vv[r] = acc[m][n][r] + bv;
        if (sec < 2) {
          unsigned short* outp = (sec == 0) ? q_out : k_out;
#pragma unroll
          for (int r = 0; r < 4; ++r) {
            const float pv = __shfl_xor(vv[r], 1, 64);
            const size_t ti = (size_t)(tt0 + r) * 64 + dd;
            const float c = pe_c[ti], s = pe_s[ti], sc = pe_sc[ti];
            float ro = (dd & 1) ? (vv[r] * c + pv * s) : (vv[r] * c - pv * s);
            ro = (sec == 0) ? ro * sc : ro / sc;
            outp[((size_t)bh * Tn + tt0 + r) * 64 + dd] = f2bf(ro);
          }
        } else {
          // V tiled: element (t,d) -> ((bh*128+(t>>4))*4+(d>>4))*256+(d&15)*16+(t&15)
          // t&15 = lg*4+r here, so the 4 values are contiguous.
          u16x4 ov;
          ov.x = f2bf(vv[0]); ov.y = f2bf(vv[1]);
          ov.z = f2bf(vv[2]); ov.w = f2bf(vv[3]);
          const size_t off = (((size_t)bh * 128 + (tt0 >> 4)) * 4 + (dd >> 4)) * 256 +
                             (size_t)(dd & 15) * 16 + (tt0 & 15);
          *(u16x4*)(v_out + off) = ov;
        }
      } else {
#pragma unroll
        for (int r = 0; r < 4; ++r) {
          const int row = bm * TM + wr * (TM / 2) + m * 16 + lg * 4 + r;
          float v = acc[m][n][r] + bv;
          if (MODE == 0) {
            obf[(size_t)row * N + col] = f2bf(v);
          } else if (MODE == 1) {
            obf[(size_t)row * N + col] = f2bf(selu_f(v));
          } else {
            const int b = row >> 11;
            const float g = cm[b * 6144 + 5 * 1024 + col];
            of32[(size_t)row * N + col] = resid[(size_t)row * N + col] + g * v;
          }
        }
      }
    }
  }
}

// ---------------- causal flash attention ----------------
// EXACT r14-r21 kernel (verified passing 8x): swapped QK^T, in-register
// softmax, depth-1 reg pipeline, defer-max THR=8, diagonal-only masking,
// XCD-locality, complement-paired chunks, tiled-V reads. FROZEN.
#define ATTN_LOAD(KB, KF, VF)                                                          \
  do {                                                                                 \
    const int kb_ = (KB);                                                              \
    _Pragma("unroll")                                                                  \
    for (int cc = 0; cc < 2; ++cc) {                                                   \
      const unsigned short* Kp = Kbase + (size_t)(kb_ + cc * 16 + lr) * 64 + lg * 8;   \
      KF[cc][0] = *(const s16x8*)(Kp);                                                 \
      KF[cc][1] = *(const s16x8*)(Kp + 32);                                            \
    }                                                                                  \
    _Pragma("unroll")                                                                  \
    for (int dt = 0; dt < 4; ++dt)                                                     \
      _Pragma("unroll")                                                                \
      for (int cc = 0; cc < 2; ++cc)                                                   \
        VF[dt][cc] = *(const s16x4*)(Vbase + (size_t)(((kb_ >> 4) + cc) * 4 + dt) *    \
                                     256 + lr * 16 + lg * 4);                          \
  } while (0)

#define ATTN_COMP(KB, KF, VF, DOMASK)                                                  \
  do {                                                                                 \
    const int kb_ = (KB);                                                              \
    const bool dm_ = (DOMASK);                                                         \
    f32x4 st[2][2];                                                                    \
    _Pragma("unroll")                                                                  \
    for (int qt = 0; qt < 2; ++qt)                                                     \
      _Pragma("unroll")                                                                \
      for (int cc = 0; cc < 2; ++cc) {                                                 \
        f32x4 t = (f32x4){0.f, 0.f, 0.f, 0.f};                                         \
        t = __builtin_amdgcn_mfma_f32_16x16x32_bf16(KF[cc][0], qa[qt][0], t, 0, 0, 0); \
        t = __builtin_amdgcn_mfma_f32_16x16x32_bf16(KF[cc][1], qa[qt][1], t, 0, 0, 0); \
        st[qt][cc] = t;                                                                \
      }                                                                                \
    _Pragma("unroll")                                                                  \
    for (int qt = 0; qt < 2; ++qt) {                                                   \
      const int q = q0w + qt * 16 + lr;                                                \
      float tmax = -1e30f;                                                             \
      _Pragma("unroll")                                                                \
      for (int cc = 0; cc < 2; ++cc)                                                   \
        _Pragma("unroll")                                                              \
        for (int r = 0; r < 4; ++r) {                                                  \
          float s = st[qt][cc][r] * inv_tp;                                            \
          if (dm_) {                                                                   \
            const int key = kb_ + cc * 16 + lg * 4 + r;                                \
            if (key > q) s = -1e30f;                                                   \
          }                                                                            \
          st[qt][cc][r] = s;                                                           \
          tmax = fmaxf(tmax, s);                                                       \
        }                                                                              \
      tmax = fmaxf(tmax, __shfl_xor(tmax, 16, 64));                                    \
      tmax = fmaxf(tmax, __shfl_xor(tmax, 32, 64));                                    \
      if (__any(tmax > mrow[qt] + 8.f)) {                                              \
        const float mn = fmaxf(mrow[qt], tmax);                                        \
        const float alpha = __expf(mrow[qt] - mn);                                     \
        mrow[qt] = mn;                                                                 \
        lsum[qt] *= alpha;                                                             \
        _Pragma("unroll")                                                              \
        for (int dt = 0; dt < 4; ++dt)                                                 \
          _Pragma("unroll")                                                            \
          for (int r = 0; r < 4; ++r) o[qt][dt][r] *= alpha;                           \
      }                                                                                \
      float p[2][4];                                                                   \
      float part = 0.f;                                                                \
      _Pragma("unroll")                                                                \
      for (int cc = 0; cc < 2; ++cc)                                                   \
        _Pragma("unroll")                                                              \
        for (int r = 0; r < 4; ++r) {                                                  \
          p[cc][r] = __expf(st[qt][cc][r] - mrow[qt]);                                 \
          part += p[cc][r];                                                            \
        }                                                                              \
      part += __shfl_xor(part, 16, 64);                                                \
      part += __shfl_xor(part, 32, 64);                                                \
      lsum[qt] += part;                                                                \
      s16x4 pb[2];                                                                     \
      _Pragma("unroll")                                                                \
      for (int cc = 0; cc < 2; ++cc) {                                                 \
        union { unsigned int u[2]; s16x4 v; } pk;                                      \
        pk.u[0] = cvt_pk_bf16(p[cc][0], p[cc][1]);                                     \
        pk.u[1] = cvt_pk_bf16(p[cc][2], p[cc][3]);                                     \
        pb[cc] = pk.v;                                                                 \
      }                                                                                \
      _Pragma("unroll")                                                                \
      for (int dt = 0; dt < 4; ++dt)                                                   \
        _Pragma("unroll")                                                              \
        for (int cc = 0; cc < 2; ++cc)                                                 \
          o[qt][dt] = mfma16_bf16(VF[dt][cc], pb[cc], o[qt][dt]);                      \
    }                                                                                  \
  } while (0)

__global__ __launch_bounds__(256) void attn_kernel(
    const unsigned short* __restrict__ Q, const unsigned short* __restrict__ Kb,
    const unsigned short* __restrict__ Vt, const float* __restrict__ x,
    const float* __restrict__ cm, float* __restrict__ x2) {
  const int blk = blockIdx.x;
  const int xcd = blk & 7, idx = blk >> 3;
  const int bh = xcd + 8 * (idx & 3);     // 4 heads per XCD
  const int s_ = idx >> 2;                // 0..15 chunk selector
  // complement pairing: co-resident pair (s_, s_+8) gets chunks (15-s_, s_)
  // summing to 15 -> uniform 80 tile-units per CU.
  const int qchunk = (s_ < 8) ? (15 - s_) : (s_ - 8);
  const int b = bh >> 4, h = bh & 15;
  const int tid = threadIdx.x;
  const int w = tid >> 6, l = tid & 63;
  const int lr = l & 15, lg = l >> 4;
  const int q0w = qchunk * 128 + w * 32;  // wave's 32 queries
  const float inv_tp = 0.08838834764831845f;  // 1/sqrt(2*64)

  const unsigned short* Kbase = Kb + (size_t)bh * Tn * 64;
  const unsigned short* Vbase = Vt + (size_t)bh * Tn * 64;  // tiled layout, same size

  // Q fragments (B-operand of swapped QK^T): lane reads Q[q][d-chunk]
  const unsigned short* Qp = Q + ((size_t)bh * Tn + q0w) * 64;
  s16x8 qa[2][2];
#pragma unroll
  for (int qt = 0; qt < 2; ++qt) {
    qa[qt][0] = *(const s16x8*)(Qp + (qt * 16 + lr) * 64 + lg * 8);
    qa[qt][1] = *(const s16x8*)(Qp + (qt * 16 + lr) * 64 + 32 + lg * 8);
  }

  f32x4 o[2][4];  // O^T per q-tile: lane holds d = dt*16+lg*4+r, q = q0w+qt*16+lr
#pragma unroll
  for (int qt = 0; qt < 2; ++qt)
#pragma unroll
    for (int dt = 0; dt < 4; ++dt) o[qt][dt] = (f32x4){0.f, 0.f, 0.f, 0.f};
  float mrow[2] = {-1e30f, -1e30f}, lsum[2] = {0.f, 0.f};

  const int N = (q0w >> 5) + 1;  // tiles; last one is diagonal (masked)
  s16x8 kf0[2][2], kf1[2][2];
  s16x4 vf0[4][2], vf1[4][2];

  ATTN_LOAD(0, kf0, vf0);
  int kt = 0;
  for (; kt + 2 <= N; kt += 2) {
    ATTN_LOAD((kt + 1) * 32, kf1, vf1);
    ATTN_COMP(kt * 32, kf0, vf0, false);        // kt <= N-2: never diagonal
    if (kt + 2 < N) ATTN_LOAD((kt + 2) * 32, kf0, vf0);
    ATTN_COMP((kt + 1) * 32, kf1, vf1, kt + 1 == N - 1);
  }
  if (kt < N) ATTN_COMP(kt * 32, kf0, vf0, true);  // odd N: last tile

  // epilogue: normalize, gate, residual. lane: q = q0w+qt*16+lr, d = dt*16+lg*4+r
#pragma unroll
  for (int qt = 0; qt < 2; ++qt) {
    const float rinv = 1.f / lsum[qt];
    const int q = q0w + qt * 16 + lr;
#pragma unroll
    for (int dt = 0; dt < 4; ++dt) {
      const int colb = h * 64 + dt * 16 + lg * 4;
      const size_t idx2 = ((size_t)b * Tn + q) * Cn + colb;
      float4 xv = *(const float4*)(x + idx2);
      float4 gv = *(const float4*)(cm + b * 6144 + 2048 + colb);
      float4 ov;
      ov.x = xv.x + gv.x * o[qt][dt][0] * rinv;
      ov.y = xv.y + gv.y * o[qt][dt][1] * rinv;
      ov.z = xv.z + gv.z * o[qt][dt][2] * rinv;
      ov.w = xv.w + gv.w * o[qt][dt][3] * rinv;
      *(float4*)(x2 + idx2) = ov;
    }
  }
}

// ---------------- launch ----------------
extern "C" void kernel_launch(void* const* d_in, const int* in_sizes, int n_in,
                              void* d_out, int out_size, void* d_ws, size_t ws_size,
                              hipStream_t stream) {
  (void)in_sizes; (void)n_in; (void)out_size; (void)ws_size;
  const float* x = (const float*)d_in[0];
  const float* pe_cos = (const float*)d_in[1];
  const float* pe_sin = (const float*)d_in[2];
  const float* pe_scale = (const float*)d_in[3];
  const float* cc = (const float*)d_in[4];
  // d_in[5] = mask: causal, computed analytically
  const float* qkv_w = (const float*)d_in[6];
  const float* qkv_b = (const float*)d_in[7];
  const float* w1 = (const float*)d_in[8];
  const float* b1 = (const float*)d_in[9];
  const float* w2 = (const float*)d_in[10];
  const float* b2 = (const float*)d_in[11];
  const float* ada_w = (const float*)d_in[12];
  const float* ada_b = (const float*)d_in[13];
  float* out = (float*)d_out;
  char* ws = (char*)d_ws;

  unsigned short* qkvw_bf = (unsigned short*)(ws + 0);
  unsigned short* w1_bf = (unsigned short*)(ws + 6291456);
  unsigned short* w2_bf = (unsigned short*)(ws + 14680064);
  float* cm = (float*)(ws + 23068672);
  unsigned short* h1 = (unsigned short*)(ws + 23117824);   // reused as h2
  unsigned short* ff1b = (unsigned short*)(ws + 31506432);
  unsigned short* Qb = (unsigned short*)(ws + 56672256);
  unsigned short* Kb2 = (unsigned short*)(ws + 65060864);
  unsigned short* Vtb = (unsigned short*)(ws + 73449472);
  float* x2b = (float*)(ws + 81838080);
  // total ws use: 98,615,296 bytes

  prep_kernel<<<12800, 256, 0, stream>>>(qkv_w, w1, w2, qkvw_bf, w1_bf, w2_bf,
                                         cc, ada_w, ada_b, cm);
  ln_mod<<<4096, 256, 0, stream>>>(x, cm, h1, 0, 1024);
  gemm_bt<3, 128, 32><<<dim3(24, 32), 256, 0, stream>>>(
      h1, qkvw_bf, qkv_b, nullptr, nullptr, nullptr, nullptr, 4096, 3072, 1024,
      pe_cos, pe_sin, pe_scale, Qb, Kb2, Vtb);
  attn_kernel<<<512, 256, 0, stream>>>(Qb, Kb2, Vtb, x, cm, x2b);
  ln_mod<<<4096, 256, 0, stream>>>(x2b, cm, h1, 3072, 4096);
  gemm_bt<1, 128, 64><<<dim3(32, 32), 256, 0, stream>>>(
      h1, w1_bf, b1, ff1b, nullptr, nullptr, nullptr, 4096, 4096, 1024,
      nullptr, nullptr, nullptr, nullptr, nullptr, nullptr);
  gemm_bt<2, 64, 64><<<dim3(8, 64), 256, 0, stream>>>(
      ff1b, w2_bf, b2, nullptr, out, x2b, cm, 4096, 1024, 4096,
      nullptr, nullptr, nullptr, nullptr, nullptr, nullptr);
}

// Round 23
// 237.908 us; speedup vs baseline: 1.0823x; 1.0058x over previous
//
#include <hip/hip_runtime.h>

#define Bn 2
#define Tn 2048
#define Cn 1024
#define NHn 16

typedef __attribute__((ext_vector_type(8))) short s16x8;
typedef __attribute__((ext_vector_type(4))) short s16x4;
typedef __attribute__((ext_vector_type(4))) float f32x4;
typedef __attribute__((ext_vector_type(8))) unsigned short u16x8;
typedef __attribute__((ext_vector_type(4))) unsigned short u16x4;
typedef const __attribute__((address_space(1))) void* gas_t;
typedef __attribute__((address_space(3))) void* las_t;

__device__ __forceinline__ void gl_lds16(const void* g, void* l) {
  __builtin_amdgcn_global_load_lds((gas_t)g, (las_t)l, 16, 0, 0);
}

__device__ __forceinline__ float bf2f(unsigned short u) {
  unsigned int x = ((unsigned int)u) << 16;
  float f; __builtin_memcpy(&f, &x, 4); return f;
}
__device__ __forceinline__ unsigned short f2bf(float f) {
  unsigned int x; __builtin_memcpy(&x, &f, 4);
  x += 0x7fffu + ((x >> 16) & 1u);
  return (unsigned short)(x >> 16);
}
__device__ __forceinline__ unsigned int cvt_pk_bf16(float a, float b) {
  unsigned int r;
  asm("v_cvt_pk_bf16_f32 %0, %1, %2" : "=v"(r) : "v"(a), "v"(b));
  return r;
}
// 16x16x16 bf16 MFMA; __has_builtin check inside the body so the HOST pass
// (where the amdgcn builtin doesn't exist) still parses.
__device__ __forceinline__ f32x4 mfma16_bf16(s16x4 a, s16x4 b, f32x4 c) {
#if defined(__has_builtin)
#if __has_builtin(__builtin_amdgcn_mfma_f32_16x16x16bf16_1k)
  return __builtin_amdgcn_mfma_f32_16x16x16bf16_1k(a, b, c, 0, 0, 0);
#else
  return c;  // host-pass parse only; device pass has the builtin (verified r3/r5)
#endif
#else
  return c;
#endif
}
__device__ __forceinline__ float selu_f(float x) {
  const float SC = 1.0507009873554805f, AL = 1.6732632423543772f;
  return x > 0.f ? SC * x : SC * AL * (__expf(x) - 1.f);
}
__device__ __forceinline__ float waveRS(float v) {
#pragma unroll
  for (int m = 32; m; m >>= 1) v += __shfl_xor(v, m, 64);
  return v;
}

// LDS K-chunk swizzle (rule 21, both-sides): verified BK=32 form (r15) and
// BK=64 form (r16-r18); bank-conflict counter = 0 for both.
template <int BK>
__device__ __forceinline__ int swz_stage(int row, int sl) {
  if constexpr (BK == 32) return sl ^ ((row >> 1) & 3);
  else return sl ^ (row & 7);
}
template <int BK>
__device__ __forceinline__ int swz_read(int rr, int kk, int lg) {
  if constexpr (BK == 32) return lg ^ ((rr >> 1) & 3);
  else return (kk * 4 + lg) ^ (rr & 7);
}

// ---------------- prep: 3 weight casts + modulation in ONE dispatch ----------------
__global__ __launch_bounds__(256) void prep_kernel(
    const float* __restrict__ qkv_w, const float* __restrict__ w1,
    const float* __restrict__ w2, unsigned short* __restrict__ qkvw_bf,
    unsigned short* __restrict__ w1_bf, unsigned short* __restrict__ w2_bf,
    const float* __restrict__ cin, const float* __restrict__ ada_w,
    const float* __restrict__ ada_b, float* __restrict__ cm) {
  const int blk = blockIdx.x;
  const int tid = threadIdx.x;
  if (blk < 11264) {
    const float* in; unsigned short* out; size_t base;
    if (blk < 3072)      { in = qkv_w; out = qkvw_bf; base = (size_t)blk * 1024; }
    else if (blk < 7168) { in = w1;    out = w1_bf;   base = (size_t)(blk - 3072) * 1024; }
    else                 { in = w2;    out = w2_bf;   base = (size_t)(blk - 7168) * 1024; }
    size_t i = base + (size_t)tid * 4;
    float4 v = *(const float4*)(in + i);
    u16x4 o;
    o.x = f2bf(v.x); o.y = f2bf(v.y); o.z = f2bf(v.z); o.w = f2bf(v.w);
    *(u16x4*)(out + i) = o;
  } else {
    const int w = tid >> 6, l = tid & 63;
    const int j = (blk - 11264) * 4 + w;       // 0..6143
    __shared__ float sc[2][1024];
#pragma unroll
    for (int i = 0; i < 4; ++i) {
      int idx = i * 256 + tid;
      sc[0][idx] = selu_f(cin[idx]);
      sc[1][idx] = selu_f(cin[1024 + idx]);
    }
    __syncthreads();
    const float* wr_ = ada_w + (size_t)j * 1024;
    float a0 = 0.f, a1 = 0.f;
#pragma unroll
    for (int i = 0; i < 4; ++i) {
      float4 wv = *(const float4*)(wr_ + (i * 64 + l) * 4);
      const float* s0 = sc[0] + (i * 64 + l) * 4;
      const float* s1 = sc[1] + (i * 64 + l) * 4;
      a0 += wv.x * s0[0] + wv.y * s0[1] + wv.z * s0[2] + wv.w * s0[3];
      a1 += wv.x * s1[0] + wv.y * s1[1] + wv.z * s1[2] + wv.w * s1[3];
    }
    a0 = waveRS(a0);
    a1 = waveRS(a1);
    if (l == 0) {
      const float bb = ada_b[j];
      cm[j] = a0 + bb;
      cm[6144 + j] = a1 + bb;
    }
  }
}

// ---------------- LN + AdaLN modulate -> bf16 (f32 or bf16 input) ----------------
template <bool BF16IN>
__global__ __launch_bounds__(256) void ln_mod(
    const void* __restrict__ xin_, const float* __restrict__ cm,
    unsigned short* __restrict__ hout, int shift_off, int scale_off) {
  const int tid = threadIdx.x;
  const int row = blockIdx.x;
  const int b = row >> 11;
  float v[4]; float s = 0.f, s2 = 0.f;
  if constexpr (BF16IN) {
    const unsigned short* xr = (const unsigned short*)xin_ + (size_t)row * 1024;
#pragma unroll
    for (int i = 0; i < 4; ++i) {
      v[i] = bf2f(xr[i * 256 + tid]); s += v[i]; s2 += v[i] * v[i];
    }
  } else {
    const float* xr = (const float*)xin_ + (size_t)row * 1024;
#pragma unroll
    for (int i = 0; i < 4; ++i) {
      v[i] = xr[i * 256 + tid]; s += v[i]; s2 += v[i] * v[i];
    }
  }
  __shared__ float rs[8];
  s = waveRS(s); s2 = waveRS(s2);
  const int w = tid >> 6, l = tid & 63;
  if (l == 0) { rs[w] = s; rs[4 + w] = s2; }
  __syncthreads();
  s = rs[0] + rs[1] + rs[2] + rs[3];
  s2 = rs[4] + rs[5] + rs[6] + rs[7];
  float mean = s * (1.f / 1024.f);
  float var = s2 * (1.f / 1024.f) - mean * mean;
  float rstd = rsqrtf(var + 1e-6f);
  const float* cb = cm + b * 6144;
#pragma unroll
  for (int i = 0; i < 4; ++i) {
    int ch = i * 256 + tid;
    float hv = (v[i] - mean) * rstd * (1.f + cb[scale_off + ch]) + cb[shift_off + ch];
    hout[(size_t)row * 1024 + ch] = f2bf(hv);
  }
}

// ---------------- GEMM: out[M][N] = A[M][K](bf16) * Bw[N][K](bf16)^T ----------------
// MODE 0: +bias -> bf16 ; MODE 1: selu(+bias) -> bf16
// MODE 2: x2(bf16) + gate_f*(+bias) -> f32
// MODE 3: qkv fused epilogue (+bias, RoPE, scatter Q/K/tiled-V) — r22-verified.
// TM: tile rows (128/64). BK: K-step (32/64). 2-phase double-buffer with
// T4 COUNTED vmcnt + raw barriers; both-sides LDS XOR swizzle; XCD swizzle.
template <int MODE, int TM, int BK>
__global__ __launch_bounds__(256) void gemm_bt(
    const unsigned short* __restrict__ A, const unsigned short* __restrict__ Bw,
    const float* __restrict__ bias, unsigned short* __restrict__ obf,
    float* __restrict__ of32, const unsigned short* __restrict__ resid,
    const float* __restrict__ cm, int M, int N, int K,
    const float* __restrict__ pe_c, const float* __restrict__ pe_s,
    const float* __restrict__ pe_sc, unsigned short* __restrict__ q_out,
    unsigned short* __restrict__ k_out, unsigned short* __restrict__ v_out) {
  constexpr int MR = TM / 32;           // 16-row m-tiles per wave (4 or 2)
  constexpr int CPR = BK / 8;           // 8-elem chunks per row
  constexpr int ACH = TM * BK / 2048;   // A staging chunks per K-step
  constexpr int BCH = 128 * BK / 2048;  // B staging chunks per K-step
  constexpr int KK = BK / 32;           // MFMA K-substeps
  constexpr int LPI = ACH + BCH;        // gl_lds16 issued per stage
  __shared__ unsigned short As[2 * TM * BK];
  __shared__ unsigned short Bs[2 * 128 * BK];
  const int tid = threadIdx.x;
  const int gx = gridDim.x;
  int flat = blockIdx.y * gx + blockIdx.x;
  const int cpx = (gx * gridDim.y) >> 3;   // chunks per XCD
  flat = (flat & 7) * cpx + (flat >> 3);   // XCD-contiguous remap (bijective)
  const int bm = flat / gx, bn = flat % gx;
  const int w = tid >> 6, l = tid & 63;
  const int wr = w >> 1, wc = w & 1;
  const int lr = l & 15, lg = l >> 4;

  f32x4 acc[MR][4];
#pragma unroll
  for (int m = 0; m < MR; ++m)
#pragma unroll
    for (int n = 0; n < 4; ++n) acc[m][n] = (f32x4){0.f, 0.f, 0.f, 0.f};

  const size_t abase = (size_t)bm * TM * K;
  const size_t bbase = (size_t)bn * 128 * K;

#define GEMM_STAGE(KT, HALF)                                                        \
  do {                                                                              \
    const int ko_ = (KT) * BK;                                                      \
    const int hf_ = (HALF);                                                         \
    _Pragma("unroll")                                                               \
    for (int j = 0; j < ACH; ++j) {                                                 \
      const int c = tid + j * 256;                                                  \
      const int row_ = c / CPR, sl_ = c % CPR;                                      \
      const int kcg = swz_stage<BK>(row_, sl_);                                     \
      gl_lds16(A + abase + (size_t)row_ * K + kcg * 8 + ko_,                        \
               As + hf_ * TM * BK + c * 8);                                         \
    }                                                                               \
    _Pragma("unroll")                                                               \
    for (int j = 0; j < BCH; ++j) {                                                 \
      const int c = tid + j * 256;                                                  \
      const int row_ = c / CPR, sl_ = c % CPR;                                      \
      const int kcg = swz_stage<BK>(row_, sl_);                                     \
      gl_lds16(Bw + bbase + (size_t)row_ * K + kcg * 8 + ko_,                       \
               Bs + hf_ * 128 * BK + c * 8);                                        \
    }                                                                               \
  } while (0)

  const int nkt = K / BK;
  GEMM_STAGE(0, 0);
  for (int kt = 0; kt < nkt; ++kt) {
    const int cur = kt & 1;
    if (kt + 1 < nkt) {
      GEMM_STAGE(kt + 1, cur ^ 1);
      asm volatile("s_waitcnt vmcnt(%0)" ::"n"(LPI) : "memory");
    } else {
      asm volatile("s_waitcnt vmcnt(0)" ::: "memory");
    }
    __builtin_amdgcn_sched_barrier(0);
    __builtin_amdgcn_s_barrier();  // all waves: buf[cur] fully staged
    __builtin_amdgcn_sched_barrier(0);
    s16x8 af[MR][KK], bf[4][KK];
#pragma unroll
    for (int m = 0; m < MR; ++m) {
      const int rr = wr * (TM / 2) + m * 16 + lr;
#pragma unroll
      for (int kk = 0; kk < KK; ++kk) {
        const int kc = swz_read<BK>(rr, kk, lg);
        af[m][kk] = *(const s16x8*)(As + cur * TM * BK + rr * BK + kc * 8);
      }
    }
#pragma unroll
    for (int n = 0; n < 4; ++n) {
      const int rr = wc * 64 + n * 16 + lr;
#pragma unroll
      for (int kk = 0; kk < KK; ++kk) {
        const int kc = swz_read<BK>(rr, kk, lg);
        bf[n][kk] = *(const s16x8*)(Bs + cur * 128 * BK + rr * BK + kc * 8);
      }
    }
#pragma unroll
    for (int kk = 0; kk < KK; ++kk)
#pragma unroll
      for (int m = 0; m < MR; ++m)
#pragma unroll
        for (int n = 0; n < 4; ++n)
          acc[m][n] = __builtin_amdgcn_mfma_f32_16x16x32_bf16(af[m][kk], bf[n][kk], acc[m][n], 0, 0, 0);
    asm volatile("" ::: "memory");
    __builtin_amdgcn_s_barrier();  // all waves done reading buf[cur]
    __builtin_amdgcn_sched_barrier(0);
  }
#undef GEMM_STAGE

#pragma unroll
  for (int m = 0; m < MR; ++m) {
#pragma unroll
    for (int n = 0; n < 4; ++n) {
      const int col = bn * 128 + wc * 64 + n * 16 + lr;
      const float bv = bias[col];
      if (MODE == 3) {
        // wave-uniform per (m,n): section / head (16-col span never crosses
        // a 64-boundary); d parity == lr parity, RoPE pair lives in lane lr^1.
        const int row0 = bm * TM + wr * (TM / 2) + m * 16 + lg * 4;
        const int sec = col >> 10;           // 0=Q 1=K 2=V
        const int cc2 = col & 1023;
        const int hh = cc2 >> 6, dd = cc2 & 63;
        const int bb = row0 >> 11;
        const int tt0 = row0 & 2047;
        const int bh = bb * 16 + hh;
        float vv[4];
#pragma unroll
        for (int r = 0; r < 4; ++r) vv[r] = acc[m][n][r] + bv;
        if (sec < 2) {
          unsigned short* outp = (sec == 0) ? q_out : k_out;
#pragma unroll
          for (int r = 0; r < 4; ++r) {
            const float pv = __shfl_xor(vv[r], 1, 64);
            const size_t ti = (size_t)(tt0 + r) * 64 + dd;
            const float c = pe_c[ti], s = pe_s[ti], sc = pe_sc[ti];
            float ro = (dd & 1) ? (vv[r] * c + pv * s) : (vv[r] * c - pv * s);
            ro = (sec == 0) ? ro * sc : ro / sc;
            outp[((size_t)bh * Tn + tt0 + r) * 64 + dd] = f2bf(ro);
          }
        } else {
          u16x4 ov;
          ov.x = f2bf(vv[0]); ov.y = f2bf(vv[1]);
          ov.z = f2bf(vv[2]); ov.w = f2bf(vv[3]);
          const size_t off = (((size_t)bh * 128 + (tt0 >> 4)) * 4 + (dd >> 4)) * 256 +
                             (size_t)(dd & 15) * 16 + (tt0 & 15);
          *(u16x4*)(v_out + off) = ov;
        }
      } else {
#pragma unroll
        for (int r = 0; r < 4; ++r) {
          const int row = bm * TM + wr * (TM / 2) + m * 16 + lg * 4 + r;
          float v = acc[m][n][r] + bv;
          if (MODE == 0) {
            obf[(size_t)row * N + col] = f2bf(v);
          } else if (MODE == 1) {
            obf[(size_t)row * N + col] = f2bf(selu_f(v));
          } else {
            const int b = row >> 11;
            const float g = cm[b * 6144 + 5 * 1024 + col];
            of32[(size_t)row * N + col] = bf2f(resid[(size_t)row * N + col]) + g * v;
          }
        }
      }
    }
  }
}

// ---------------- causal flash attention ----------------
// r14-r22 core (verified passing 9x); ONLY change: x2 written as bf16
// (u16x4) instead of f32 — halves the x2 write + downstream reads.
#define ATTN_LOAD(KB, KF, VF)                                                          \
  do {                                                                                 \
    const int kb_ = (KB);                                                              \
    _Pragma("unroll")                                                                  \
    for (int cc = 0; cc < 2; ++cc) {                                                   \
      const unsigned short* Kp = Kbase + (size_t)(kb_ + cc * 16 + lr) * 64 + lg * 8;   \
      KF[cc][0] = *(const s16x8*)(Kp);                                                 \
      KF[cc][1] = *(const s16x8*)(Kp + 32);                                            \
    }                                                                                  \
    _Pragma("unroll")                                                                  \
    for (int dt = 0; dt < 4; ++dt)                                                     \
      _Pragma("unroll")                                                                \
      for (int cc = 0; cc < 2; ++cc)                                                   \
        VF[dt][cc] = *(const s16x4*)(Vbase + (size_t)(((kb_ >> 4) + cc) * 4 + dt) *    \
                                     256 + lr * 16 + lg * 4);                          \
  } while (0)

#define ATTN_COMP(KB, KF, VF, DOMASK)                                                  \
  do {                                                                                 \
    const int kb_ = (KB);                                                              \
    const bool dm_ = (DOMASK);                                                         \
    f32x4 st[2][2];                                                                    \
    _Pragma("unroll")                                                                  \
    for (int qt = 0; qt < 2; ++qt)                                                     \
      _Pragma("unroll")                                                                \
      for (int cc = 0; cc < 2; ++cc) {                                                 \
        f32x4 t = (f32x4){0.f, 0.f, 0.f, 0.f};                                         \
        t = __builtin_amdgcn_mfma_f32_16x16x32_bf16(KF[cc][0], qa[qt][0], t, 0, 0, 0); \
        t = __builtin_amdgcn_mfma_f32_16x16x32_bf16(KF[cc][1], qa[qt][1], t, 0, 0, 0); \
        st[qt][cc] = t;                                                                \
      }                                                                                \
    _Pragma("unroll")                                                                  \
    for (int qt = 0; qt < 2; ++qt) {                                                   \
      const int q = q0w + qt * 16 + lr;                                                \
      float tmax = -1e30f;                                                             \
      _Pragma("unroll")                                                                \
      for (int cc = 0; cc < 2; ++cc)                                                   \
        _Pragma("unroll")                                                              \
        for (int r = 0; r < 4; ++r) {                                                  \
          float s = st[qt][cc][r] * inv_tp;                                            \
          if (dm_) {                                                                   \
            const int key = kb_ + cc * 16 + lg * 4 + r;                                \
            if (key > q) s = -1e30f;                                                   \
          }                                                                            \
          st[qt][cc][r] = s;                                                           \
          tmax = fmaxf(tmax, s);                                                       \
        }                                                                              \
      tmax = fmaxf(tmax, __shfl_xor(tmax, 16, 64));                                    \
      tmax = fmaxf(tmax, __shfl_xor(tmax, 32, 64));                                    \
      if (__any(tmax > mrow[qt] + 8.f)) {                                              \
        const float mn = fmaxf(mrow[qt], tmax);                                        \
        const float alpha = __expf(mrow[qt] - mn);                                     \
        mrow[qt] = mn;                                                                 \
        lsum[qt] *= alpha;                                                             \
        _Pragma("unroll")                                                              \
        for (int dt = 0; dt < 4; ++dt)                                                 \
          _Pragma("unroll")                                                            \
          for (int r = 0; r < 4; ++r) o[qt][dt][r] *= alpha;                           \
      }                                                                                \
      float p[2][4];                                                                   \
      float part = 0.f;                                                                \
      _Pragma("unroll")                                                                \
      for (int cc = 0; cc < 2; ++cc)                                                   \
        _Pragma("unroll")                                                              \
        for (int r = 0; r < 4; ++r) {                                                  \
          p[cc][r] = __expf(st[qt][cc][r] - mrow[qt]);                                 \
          part += p[cc][r];                                                            \
        }                                                                              \
      part += __shfl_xor(part, 16, 64);                                                \
      part += __shfl_xor(part, 32, 64);                                                \
      lsum[qt] += part;                                                                \
      s16x4 pb[2];                                                                     \
      _Pragma("unroll")                                                                \
      for (int cc = 0; cc < 2; ++cc) {                                                 \
        union { unsigned int u[2]; s16x4 v; } pk;                                      \
        pk.u[0] = cvt_pk_bf16(p[cc][0], p[cc][1]);                                     \
        pk.u[1] = cvt_pk_bf16(p[cc][2], p[cc][3]);                                     \
        pb[cc] = pk.v;                                                                 \
      }                                                                                \
      _Pragma("unroll")                                                                \
      for (int dt = 0; dt < 4; ++dt)                                                   \
        _Pragma("unroll")                                                              \
        for (int cc = 0; cc < 2; ++cc)                                                 \
          o[qt][dt] = mfma16_bf16(VF[dt][cc], pb[cc], o[qt][dt]);                      \
    }                                                                                  \
  } while (0)

__global__ __launch_bounds__(256) void attn_kernel(
    const unsigned short* __restrict__ Q, const unsigned short* __restrict__ Kb,
    const unsigned short* __restrict__ Vt, const float* __restrict__ x,
    const float* __restrict__ cm, unsigned short* __restrict__ x2) {
  const int blk = blockIdx.x;
  const int xcd = blk & 7, idx = blk >> 3;
  const int bh = xcd + 8 * (idx & 3);     // 4 heads per XCD
  const int s_ = idx >> 2;                // 0..15 chunk selector
  const int qchunk = (s_ < 8) ? (15 - s_) : (s_ - 8);
  const int b = bh >> 4, h = bh & 15;
  const int tid = threadIdx.x;
  const int w = tid >> 6, l = tid & 63;
  const int lr = l & 15, lg = l >> 4;
  const int q0w = qchunk * 128 + w * 32;  // wave's 32 queries
  const float inv_tp = 0.08838834764831845f;  // 1/sqrt(2*64)

  const unsigned short* Kbase = Kb + (size_t)bh * Tn * 64;
  const unsigned short* Vbase = Vt + (size_t)bh * Tn * 64;  // tiled layout, same size

  const unsigned short* Qp = Q + ((size_t)bh * Tn + q0w) * 64;
  s16x8 qa[2][2];
#pragma unroll
  for (int qt = 0; qt < 2; ++qt) {
    qa[qt][0] = *(const s16x8*)(Qp + (qt * 16 + lr) * 64 + lg * 8);
    qa[qt][1] = *(const s16x8*)(Qp + (qt * 16 + lr) * 64 + 32 + lg * 8);
  }

  f32x4 o[2][4];  // O^T per q-tile: lane holds d = dt*16+lg*4+r, q = q0w+qt*16+lr
#pragma unroll
  for (int qt = 0; qt < 2; ++qt)
#pragma unroll
    for (int dt = 0; dt < 4; ++dt) o[qt][dt] = (f32x4){0.f, 0.f, 0.f, 0.f};
  float mrow[2] = {-1e30f, -1e30f}, lsum[2] = {0.f, 0.f};

  const int N = (q0w >> 5) + 1;  // tiles; last one is diagonal (masked)
  s16x8 kf0[2][2], kf1[2][2];
  s16x4 vf0[4][2], vf1[4][2];

  ATTN_LOAD(0, kf0, vf0);
  int kt = 0;
  for (; kt + 2 <= N; kt += 2) {
    ATTN_LOAD((kt + 1) * 32, kf1, vf1);
    ATTN_COMP(kt * 32, kf0, vf0, false);        // kt <= N-2: never diagonal
    if (kt + 2 < N) ATTN_LOAD((kt + 2) * 32, kf0, vf0);
    ATTN_COMP((kt + 1) * 32, kf1, vf1, kt + 1 == N - 1);
  }
  if (kt < N) ATTN_COMP(kt * 32, kf0, vf0, true);  // odd N: last tile

  // epilogue: normalize, gate, residual -> x2 (bf16)
#pragma unroll
  for (int qt = 0; qt < 2; ++qt) {
    const float rinv = 1.f / lsum[qt];
    const int q = q0w + qt * 16 + lr;
#pragma unroll
    for (int dt = 0; dt < 4; ++dt) {
      const int colb = h * 64 + dt * 16 + lg * 4;
      const size_t idx2 = ((size_t)b * Tn + q) * Cn + colb;
      float4 xv = *(const float4*)(x + idx2);
      float4 gv = *(const float4*)(cm + b * 6144 + 2048 + colb);
      u16x4 ov;
      ov.x = f2bf(xv.x + gv.x * o[qt][dt][0] * rinv);
      ov.y = f2bf(xv.y + gv.y * o[qt][dt][1] * rinv);
      ov.z = f2bf(xv.z + gv.z * o[qt][dt][2] * rinv);
      ov.w = f2bf(xv.w + gv.w * o[qt][dt][3] * rinv);
      *(u16x4*)(x2 + idx2) = ov;
    }
  }
}

// ---------------- launch ----------------
extern "C" void kernel_launch(void* const* d_in, const int* in_sizes, int n_in,
                              void* d_out, int out_size, void* d_ws, size_t ws_size,
                              hipStream_t stream) {
  (void)in_sizes; (void)n_in; (void)out_size; (void)ws_size;
  const float* x = (const float*)d_in[0];
  const float* pe_cos = (const float*)d_in[1];
  const float* pe_sin = (const float*)d_in[2];
  const float* pe_scale = (const float*)d_in[3];
  const float* cc = (const float*)d_in[4];
  // d_in[5] = mask: causal, computed analytically
  const float* qkv_w = (const float*)d_in[6];
  const float* qkv_b = (const float*)d_in[7];
  const float* w1 = (const float*)d_in[8];
  const float* b1 = (const float*)d_in[9];
  const float* w2 = (const float*)d_in[10];
  const float* b2 = (const float*)d_in[11];
  const float* ada_w = (const float*)d_in[12];
  const float* ada_b = (const float*)d_in[13];
  float* out = (float*)d_out;
  char* ws = (char*)d_ws;

  unsigned short* qkvw_bf = (unsigned short*)(ws + 0);
  unsigned short* w1_bf = (unsigned short*)(ws + 6291456);
  unsigned short* w2_bf = (unsigned short*)(ws + 14680064);
  float* cm = (float*)(ws + 23068672);
  unsigned short* h1 = (unsigned short*)(ws + 23117824);   // reused as h2
  unsigned short* ff1b = (unsigned short*)(ws + 31506432);
  unsigned short* Qb = (unsigned short*)(ws + 56672256);
  unsigned short* Kb2 = (unsigned short*)(ws + 65060864);
  unsigned short* Vtb = (unsigned short*)(ws + 73449472);
  unsigned short* x2b = (unsigned short*)(ws + 81838080);  // bf16 now (8 MB)
  // total ws use: < 98,615,296 bytes

  prep_kernel<<<12800, 256, 0, stream>>>(qkv_w, w1, w2, qkvw_bf, w1_bf, w2_bf,
                                         cc, ada_w, ada_b, cm);
  ln_mod<false><<<4096, 256, 0, stream>>>(x, cm, h1, 0, 1024);
  gemm_bt<3, 128, 32><<<dim3(24, 32), 256, 0, stream>>>(
      h1, qkvw_bf, qkv_b, nullptr, nullptr, nullptr, nullptr, 4096, 3072, 1024,
      pe_cos, pe_sin, pe_scale, Qb, Kb2, Vtb);
  attn_kernel<<<512, 256, 0, stream>>>(Qb, Kb2, Vtb, x, cm, x2b);
  ln_mod<true><<<4096, 256, 0, stream>>>(x2b, cm, h1, 3072, 4096);
  gemm_bt<1, 128, 64><<<dim3(32, 32), 256, 0, stream>>>(
      h1, w1_bf, b1, ff1b, nullptr, nullptr, nullptr, 4096, 4096, 1024,
      nullptr, nullptr, nullptr, nullptr, nullptr, nullptr);
  gemm_bt<2, 64, 64><<<dim3(8, 64), 256, 0, stream>>>(
      ff1b, w2_bf, b2, nullptr, out, x2b, cm, 4096, 1024, 4096,
      nullptr, nullptr, nullptr, nullptr, nullptr, nullptr);
}

// Round 25
// 237.831 us; speedup vs baseline: 1.0826x; 1.0003x over previous
//
#include <hip/hip_runtime.h>

#define Bn 2
#define Tn 2048
#define Cn 1024
#define NHn 16

typedef __attribute__((ext_vector_type(8))) short s16x8;
typedef __attribute__((ext_vector_type(4))) short s16x4;
typedef __attribute__((ext_vector_type(4))) float f32x4;
typedef __attribute__((ext_vector_type(8))) unsigned short u16x8;
typedef __attribute__((ext_vector_type(4))) unsigned short u16x4;
typedef const __attribute__((address_space(1))) void* gas_t;
typedef __attribute__((address_space(3))) void* las_t;

__device__ __forceinline__ void gl_lds16(const void* g, void* l) {
  __builtin_amdgcn_global_load_lds((gas_t)g, (las_t)l, 16, 0, 0);
}

__device__ __forceinline__ float bf2f(unsigned short u) {
  unsigned int x = ((unsigned int)u) << 16;
  float f; __builtin_memcpy(&f, &x, 4); return f;
}
__device__ __forceinline__ unsigned short f2bf(float f) {
  unsigned int x; __builtin_memcpy(&x, &f, 4);
  x += 0x7fffu + ((x >> 16) & 1u);
  return (unsigned short)(x >> 16);
}
__device__ __forceinline__ unsigned int cvt_pk_bf16(float a, float b) {
  unsigned int r;
  asm("v_cvt_pk_bf16_f32 %0, %1, %2" : "=v"(r) : "v"(a), "v"(b));
  return r;
}
// 16x16x16 bf16 MFMA; __has_builtin check inside the body so the HOST pass
// (where the amdgcn builtin doesn't exist) still parses.
__device__ __forceinline__ f32x4 mfma16_bf16(s16x4 a, s16x4 b, f32x4 c) {
#if defined(__has_builtin)
#if __has_builtin(__builtin_amdgcn_mfma_f32_16x16x16bf16_1k)
  return __builtin_amdgcn_mfma_f32_16x16x16bf16_1k(a, b, c, 0, 0, 0);
#else
  return c;  // host-pass parse only; device pass has the builtin (verified r3/r5)
#endif
#else
  return c;
#endif
}
__device__ __forceinline__ float selu_f(float x) {
  const float SC = 1.0507009873554805f, AL = 1.6732632423543772f;
  return x > 0.f ? SC * x : SC * AL * (__expf(x) - 1.f);
}
__device__ __forceinline__ float waveRS(float v) {
#pragma unroll
  for (int m = 32; m; m >>= 1) v += __shfl_xor(v, m, 64);
  return v;
}

// LDS K-chunk swizzle (rule 21, both-sides): verified BK=32 form (r15) and
// BK=64 form (r16-r18); bank-conflict counter = 0 for both.
template <int BK>
__device__ __forceinline__ int swz_stage(int row, int sl) {
  if constexpr (BK == 32) return sl ^ ((row >> 1) & 3);
  else return sl ^ (row & 7);
}
template <int BK>
__device__ __forceinline__ int swz_read(int rr, int kk, int lg) {
  if constexpr (BK == 32) return lg ^ ((rr >> 1) & 3);
  else return (kk * 4 + lg) ^ (rr & 7);
}

// ---------------- prep: 3 weight casts + modulation in ONE dispatch ----------------
__global__ __launch_bounds__(256) void prep_kernel(
    const float* __restrict__ qkv_w, const float* __restrict__ w1,
    const float* __restrict__ w2, unsigned short* __restrict__ qkvw_bf,
    unsigned short* __restrict__ w1_bf, unsigned short* __restrict__ w2_bf,
    const float* __restrict__ cin, const float* __restrict__ ada_w,
    const float* __restrict__ ada_b, float* __restrict__ cm) {
  const int blk = blockIdx.x;
  const int tid = threadIdx.x;
  if (blk < 11264) {
    const float* in; unsigned short* out; size_t base;
    if (blk < 3072)      { in = qkv_w; out = qkvw_bf; base = (size_t)blk * 1024; }
    else if (blk < 7168) { in = w1;    out = w1_bf;   base = (size_t)(blk - 3072) * 1024; }
    else                 { in = w2;    out = w2_bf;   base = (size_t)(blk - 7168) * 1024; }
    size_t i = base + (size_t)tid * 4;
    float4 v = *(const float4*)(in + i);
    u16x4 o;
    o.x = f2bf(v.x); o.y = f2bf(v.y); o.z = f2bf(v.z); o.w = f2bf(v.w);
    *(u16x4*)(out + i) = o;
  } else {
    const int w = tid >> 6, l = tid & 63;
    const int j = (blk - 11264) * 4 + w;       // 0..6143
    __shared__ float sc[2][1024];
#pragma unroll
    for (int i = 0; i < 4; ++i) {
      int idx = i * 256 + tid;
      sc[0][idx] = selu_f(cin[idx]);
      sc[1][idx] = selu_f(cin[1024 + idx]);
    }
    __syncthreads();
    const float* wr_ = ada_w + (size_t)j * 1024;
    float a0 = 0.f, a1 = 0.f;
#pragma unroll
    for (int i = 0; i < 4; ++i) {
      float4 wv = *(const float4*)(wr_ + (i * 64 + l) * 4);
      const float* s0 = sc[0] + (i * 64 + l) * 4;
      const float* s1 = sc[1] + (i * 64 + l) * 4;
      a0 += wv.x * s0[0] + wv.y * s0[1] + wv.z * s0[2] + wv.w * s0[3];
      a1 += wv.x * s1[0] + wv.y * s1[1] + wv.z * s1[2] + wv.w * s1[3];
    }
    a0 = waveRS(a0);
    a1 = waveRS(a1);
    if (l == 0) {
      const float bb = ada_b[j];
      cm[j] = a0 + bb;
      cm[6144 + j] = a1 + bb;
    }
  }
}

// ---------------- LN + AdaLN modulate -> bf16 (f32 or bf16 input) ----------------
template <bool BF16IN>
__global__ __launch_bounds__(256) void ln_mod(
    const void* __restrict__ xin_, const float* __restrict__ cm,
    unsigned short* __restrict__ hout, int shift_off, int scale_off) {
  const int tid = threadIdx.x;
  const int row = blockIdx.x;
  const int b = row >> 11;
  float v[4]; float s = 0.f, s2 = 0.f;
  if constexpr (BF16IN) {
    const unsigned short* xr = (const unsigned short*)xin_ + (size_t)row * 1024;
#pragma unroll
    for (int i = 0; i < 4; ++i) {
      v[i] = bf2f(xr[i * 256 + tid]); s += v[i]; s2 += v[i] * v[i];
    }
  } else {
    const float* xr = (const float*)xin_ + (size_t)row * 1024;
#pragma unroll
    for (int i = 0; i < 4; ++i) {
      v[i] = xr[i * 256 + tid]; s += v[i]; s2 += v[i] * v[i];
    }
  }
  __shared__ float rs[8];
  s = waveRS(s); s2 = waveRS(s2);
  const int w = tid >> 6, l = tid & 63;
  if (l == 0) { rs[w] = s; rs[4 + w] = s2; }
  __syncthreads();
  s = rs[0] + rs[1] + rs[2] + rs[3];
  s2 = rs[4] + rs[5] + rs[6] + rs[7];
  float mean = s * (1.f / 1024.f);
  float var = s2 * (1.f / 1024.f) - mean * mean;
  float rstd = rsqrtf(var + 1e-6f);
  const float* cb = cm + b * 6144;
#pragma unroll
  for (int i = 0; i < 4; ++i) {
    int ch = i * 256 + tid;
    float hv = (v[i] - mean) * rstd * (1.f + cb[scale_off + ch]) + cb[shift_off + ch];
    hout[(size_t)row * 1024 + ch] = f2bf(hv);
  }
}

// ---------------- GEMM: out[M][N] = A[M][K](bf16) * Bw[N][K](bf16)^T ----------------
// MODE 0: +bias -> bf16 ; MODE 1: selu(+bias) -> bf16
// MODE 2: x2(bf16) + gate_f*(+bias) -> f32
// MODE 3: qkv fused epilogue (+bias, RoPE, scatter Q/K/tiled-V) — r22-verified.
// TM: tile rows (128/64). BK: K-step (32/64). 2-phase double-buffer with
// T4 COUNTED vmcnt + raw barriers; both-sides LDS XOR swizzle; XCD swizzle.
template <int MODE, int TM, int BK>
__global__ __launch_bounds__(256) void gemm_bt(
    const unsigned short* __restrict__ A, const unsigned short* __restrict__ Bw,
    const float* __restrict__ bias, unsigned short* __restrict__ obf,
    float* __restrict__ of32, const unsigned short* __restrict__ resid,
    const float* __restrict__ cm, int M, int N, int K,
    const float* __restrict__ pe_c, const float* __restrict__ pe_s,
    const float* __restrict__ pe_sc, unsigned short* __restrict__ q_out,
    unsigned short* __restrict__ k_out, unsigned short* __restrict__ v_out) {
  constexpr int MR = TM / 32;           // 16-row m-tiles per wave (4 or 2)
  constexpr int CPR = BK / 8;           // 8-elem chunks per row
  constexpr int ACH = TM * BK / 2048;   // A staging chunks per K-step
  constexpr int BCH = 128 * BK / 2048;  // B staging chunks per K-step
  constexpr int KK = BK / 32;           // MFMA K-substeps
  constexpr int LPI = ACH + BCH;        // gl_lds16 issued per stage
  __shared__ unsigned short As[2 * TM * BK];
  __shared__ unsigned short Bs[2 * 128 * BK];
  const int tid = threadIdx.x;
  const int gx = gridDim.x;
  int flat = blockIdx.y * gx + blockIdx.x;
  const int cpx = (gx * gridDim.y) >> 3;   // chunks per XCD
  flat = (flat & 7) * cpx + (flat >> 3);   // XCD-contiguous remap (bijective)
  const int bm = flat / gx, bn = flat % gx;
  const int w = tid >> 6, l = tid & 63;
  const int wr = w >> 1, wc = w & 1;
  const int lr = l & 15, lg = l >> 4;

  f32x4 acc[MR][4];
#pragma unroll
  for (int m = 0; m < MR; ++m)
#pragma unroll
    for (int n = 0; n < 4; ++n) acc[m][n] = (f32x4){0.f, 0.f, 0.f, 0.f};

  const size_t abase = (size_t)bm * TM * K;
  const size_t bbase = (size_t)bn * 128 * K;

#define GEMM_STAGE(KT, HALF)                                                        \
  do {                                                                              \
    const int ko_ = (KT) * BK;                                                      \
    const int hf_ = (HALF);                                                         \
    _Pragma("unroll")                                                               \
    for (int j = 0; j < ACH; ++j) {                                                 \
      const int c = tid + j * 256;                                                  \
      const int row_ = c / CPR, sl_ = c % CPR;                                      \
      const int kcg = swz_stage<BK>(row_, sl_);                                     \
      gl_lds16(A + abase + (size_t)row_ * K + kcg * 8 + ko_,                        \
               As + hf_ * TM * BK + c * 8);                                         \
    }                                                                               \
    _Pragma("unroll")                                                               \
    for (int j = 0; j < BCH; ++j) {                                                 \
      const int c = tid + j * 256;                                                  \
      const int row_ = c / CPR, sl_ = c % CPR;                                      \
      const int kcg = swz_stage<BK>(row_, sl_);                                     \
      gl_lds16(Bw + bbase + (size_t)row_ * K + kcg * 8 + ko_,                       \
               Bs + hf_ * 128 * BK + c * 8);                                        \
    }                                                                               \
  } while (0)

  const int nkt = K / BK;
  GEMM_STAGE(0, 0);
  for (int kt = 0; kt < nkt; ++kt) {
    const int cur = kt & 1;
    if (kt + 1 < nkt) {
      GEMM_STAGE(kt + 1, cur ^ 1);
      asm volatile("s_waitcnt vmcnt(%0)" ::"n"(LPI) : "memory");
    } else {
      asm volatile("s_waitcnt vmcnt(0)" ::: "memory");
    }
    __builtin_amdgcn_sched_barrier(0);
    __builtin_amdgcn_s_barrier();  // all waves: buf[cur] fully staged
    __builtin_amdgcn_sched_barrier(0);
    s16x8 af[MR][KK], bf[4][KK];
#pragma unroll
    for (int m = 0; m < MR; ++m) {
      const int rr = wr * (TM / 2) + m * 16 + lr;
#pragma unroll
      for (int kk = 0; kk < KK; ++kk) {
        const int kc = swz_read<BK>(rr, kk, lg);
        af[m][kk] = *(const s16x8*)(As + cur * TM * BK + rr * BK + kc * 8);
      }
    }
#pragma unroll
    for (int n = 0; n < 4; ++n) {
      const int rr = wc * 64 + n * 16 + lr;
#pragma unroll
      for (int kk = 0; kk < KK; ++kk) {
        const int kc = swz_read<BK>(rr, kk, lg);
        bf[n][kk] = *(const s16x8*)(Bs + cur * 128 * BK + rr * BK + kc * 8);
      }
    }
#pragma unroll
    for (int kk = 0; kk < KK; ++kk)
#pragma unroll
      for (int m = 0; m < MR; ++m)
#pragma unroll
        for (int n = 0; n < 4; ++n)
          acc[m][n] = __builtin_amdgcn_mfma_f32_16x16x32_bf16(af[m][kk], bf[n][kk], acc[m][n], 0, 0, 0);
    asm volatile("" ::: "memory");
    __builtin_amdgcn_s_barrier();  // all waves done reading buf[cur]
    __builtin_amdgcn_sched_barrier(0);
  }
#undef GEMM_STAGE

#pragma unroll
  for (int m = 0; m < MR; ++m) {
#pragma unroll
    for (int n = 0; n < 4; ++n) {
      const int col = bn * 128 + wc * 64 + n * 16 + lr;
      const float bv = bias[col];
      if (MODE == 3) {
        const int row0 = bm * TM + wr * (TM / 2) + m * 16 + lg * 4;
        const int sec = col >> 10;           // 0=Q 1=K 2=V
        const int cc2 = col & 1023;
        const int hh = cc2 >> 6, dd = cc2 & 63;
        const int bb = row0 >> 11;
        const int tt0 = row0 & 2047;
        const int bh = bb * 16 + hh;
        float vv[4];
#pragma unroll
        for (int r = 0; r < 4; ++r) vv[r] = acc[m][n][r] + bv;
        if (sec < 2) {
          unsigned short* outp = (sec == 0) ? q_out : k_out;
#pragma unroll
          for (int r = 0; r < 4; ++r) {
            const float pv = __shfl_xor(vv[r], 1, 64);
            const size_t ti = (size_t)(tt0 + r) * 64 + dd;
            const float c = pe_c[ti], s = pe_s[ti], sc = pe_sc[ti];
            float ro = (dd & 1) ? (vv[r] * c + pv * s) : (vv[r] * c - pv * s);
            ro = (sec == 0) ? ro * sc : ro / sc;
            outp[((size_t)bh * Tn + tt0 + r) * 64 + dd] = f2bf(ro);
          }
        } else {
          u16x4 ov;
          ov.x = f2bf(vv[0]); ov.y = f2bf(vv[1]);
          ov.z = f2bf(vv[2]); ov.w = f2bf(vv[3]);
          const size_t off = (((size_t)bh * 128 + (tt0 >> 4)) * 4 + (dd >> 4)) * 256 +
                             (size_t)(dd & 15) * 16 + (tt0 & 15);
          *(u16x4*)(v_out + off) = ov;
        }
      } else {
#pragma unroll
        for (int r = 0; r < 4; ++r) {
          const int row = bm * TM + wr * (TM / 2) + m * 16 + lg * 4 + r;
          float v = acc[m][n][r] + bv;
          if (MODE == 0) {
            obf[(size_t)row * N + col] = f2bf(v);
          } else if (MODE == 1) {
            obf[(size_t)row * N + col] = f2bf(selu_f(v));
          } else {
            const int b = row >> 11;
            const float g = cm[b * 6144 + 5 * 1024 + col];
            of32[(size_t)row * N + col] = bf2f(resid[(size_t)row * N + col]) + g * v;
          }
        }
      }
    }
  }
}

// ---------------- causal flash attention ----------------
// EXACT r23 kernel (verified passing; session-stable form). Swapped QK^T,
// in-register softmax, depth-1 reg pipeline, defer-max THR=8, diagonal-only
// masking, XCD-locality, complement-paired chunks, tiled-V, bf16 x2. FROZEN
// — three perturbations of this kernel (r8 setprio, r10 geometry, r24 KB=64)
// produced unexplained NaNs; its exact form is load-bearing.
#define ATTN_LOAD(KB, KF, VF)                                                          \
  do {                                                                                 \
    const int kb_ = (KB);                                                              \
    _Pragma("unroll")                                                                  \
    for (int cc = 0; cc < 2; ++cc) {                                                   \
      const unsigned short* Kp = Kbase + (size_t)(kb_ + cc * 16 + lr) * 64 + lg * 8;   \
      KF[cc][0] = *(const s16x8*)(Kp);                                                 \
      KF[cc][1] = *(const s16x8*)(Kp + 32);                                            \
    }                                                                                  \
    _Pragma("unroll")                                                                  \
    for (int dt = 0; dt < 4; ++dt)                                                     \
      _Pragma("unroll")                                                                \
      for (int cc = 0; cc < 2; ++cc)                                                   \
        VF[dt][cc] = *(const s16x4*)(Vbase + (size_t)(((kb_ >> 4) + cc) * 4 + dt) *    \
                                     256 + lr * 16 + lg * 4);                          \
  } while (0)

#define ATTN_COMP(KB, KF, VF, DOMASK)                                                  \
  do {                                                                                 \
    const int kb_ = (KB);                                                              \
    const bool dm_ = (DOMASK);                                                         \
    f32x4 st[2][2];                                                                    \
    _Pragma("unroll")                                                                  \
    for (int qt = 0; qt < 2; ++qt)                                                     \
      _Pragma("unroll")                                                                \
      for (int cc = 0; cc < 2; ++cc) {                                                 \
        f32x4 t = (f32x4){0.f, 0.f, 0.f, 0.f};                                         \
        t = __builtin_amdgcn_mfma_f32_16x16x32_bf16(KF[cc][0], qa[qt][0], t, 0, 0, 0); \
        t = __builtin_amdgcn_mfma_f32_16x16x32_bf16(KF[cc][1], qa[qt][1], t, 0, 0, 0); \
        st[qt][cc] = t;                                                                \
      }                                                                                \
    _Pragma("unroll")                                                                  \
    for (int qt = 0; qt < 2; ++qt) {                                                   \
      const int q = q0w + qt * 16 + lr;                                                \
      float tmax = -1e30f;                                                             \
      _Pragma("unroll")                                                                \
      for (int cc = 0; cc < 2; ++cc)                                                   \
        _Pragma("unroll")                                                              \
        for (int r = 0; r < 4; ++r) {                                                  \
          float s = st[qt][cc][r] * inv_tp;                                            \
          if (dm_) {                                                                   \
            const int key = kb_ + cc * 16 + lg * 4 + r;                                \
            if (key > q) s = -1e30f;                                                   \
          }                                                                            \
          st[qt][cc][r] = s;                                                           \
          tmax = fmaxf(tmax, s);                                                       \
        }                                                                              \
      tmax = fmaxf(tmax, __shfl_xor(tmax, 16, 64));                                    \
      tmax = fmaxf(tmax, __shfl_xor(tmax, 32, 64));                                    \
      if (__any(tmax > mrow[qt] + 8.f)) {                                              \
        const float mn = fmaxf(mrow[qt], tmax);                                        \
        const float alpha = __expf(mrow[qt] - mn);                                     \
        mrow[qt] = mn;                                                                 \
        lsum[qt] *= alpha;                                                             \
        _Pragma("unroll")                                                              \
        for (int dt = 0; dt < 4; ++dt)                                                 \
          _Pragma("unroll")                                                            \
          for (int r = 0; r < 4; ++r) o[qt][dt][r] *= alpha;                           \
      }                                                                                \
      float p[2][4];                                                                   \
      float part = 0.f;                                                                \
      _Pragma("unroll")                                                                \
      for (int cc = 0; cc < 2; ++cc)                                                   \
        _Pragma("unroll")                                                              \
        for (int r = 0; r < 4; ++r) {                                                  \
          p[cc][r] = __expf(st[qt][cc][r] - mrow[qt]);                                 \
          part += p[cc][r];                                                            \
        }                                                                              \
      part += __shfl_xor(part, 16, 64);                                                \
      part += __shfl_xor(part, 32, 64);                                                \
      lsum[qt] += part;                                                                \
      s16x4 pb[2];                                                                     \
      _Pragma("unroll")                                                                \
      for (int cc = 0; cc < 2; ++cc) {                                                 \
        union { unsigned int u[2]; s16x4 v; } pk;                                      \
        pk.u[0] = cvt_pk_bf16(p[cc][0], p[cc][1]);                                     \
        pk.u[1] = cvt_pk_bf16(p[cc][2], p[cc][3]);                                     \
        pb[cc] = pk.v;                                                                 \
      }                                                                                \
      _Pragma("unroll")                                                                \
      for (int dt = 0; dt < 4; ++dt)                                                   \
        _Pragma("unroll")                                                              \
        for (int cc = 0; cc < 2; ++cc)                                                 \
          o[qt][dt] = mfma16_bf16(VF[dt][cc], pb[cc], o[qt][dt]);                      \
    }                                                                                  \
  } while (0)

__global__ __launch_bounds__(256) void attn_kernel(
    const unsigned short* __restrict__ Q, const unsigned short* __restrict__ Kb,
    const unsigned short* __restrict__ Vt, const float* __restrict__ x,
    const float* __restrict__ cm, unsigned short* __restrict__ x2) {
  const int blk = blockIdx.x;
  const int xcd = blk & 7, idx = blk >> 3;
  const int bh = xcd + 8 * (idx & 3);     // 4 heads per XCD
  const int s_ = idx >> 2;                // 0..15 chunk selector
  const int qchunk = (s_ < 8) ? (15 - s_) : (s_ - 8);
  const int b = bh >> 4, h = bh & 15;
  const int tid = threadIdx.x;
  const int w = tid >> 6, l = tid & 63;
  const int lr = l & 15, lg = l >> 4;
  const int q0w = qchunk * 128 + w * 32;  // wave's 32 queries
  const float inv_tp = 0.08838834764831845f;  // 1/sqrt(2*64)

  const unsigned short* Kbase = Kb + (size_t)bh * Tn * 64;
  const unsigned short* Vbase = Vt + (size_t)bh * Tn * 64;  // tiled layout, same size

  const unsigned short* Qp = Q + ((size_t)bh * Tn + q0w) * 64;
  s16x8 qa[2][2];
#pragma unroll
  for (int qt = 0; qt < 2; ++qt) {
    qa[qt][0] = *(const s16x8*)(Qp + (qt * 16 + lr) * 64 + lg * 8);
    qa[qt][1] = *(const s16x8*)(Qp + (qt * 16 + lr) * 64 + 32 + lg * 8);
  }

  f32x4 o[2][4];  // O^T per q-tile: lane holds d = dt*16+lg*4+r, q = q0w+qt*16+lr
#pragma unroll
  for (int qt = 0; qt < 2; ++qt)
#pragma unroll
    for (int dt = 0; dt < 4; ++dt) o[qt][dt] = (f32x4){0.f, 0.f, 0.f, 0.f};
  float mrow[2] = {-1e30f, -1e30f}, lsum[2] = {0.f, 0.f};

  const int N = (q0w >> 5) + 1;  // tiles; last one is diagonal (masked)
  s16x8 kf0[2][2], kf1[2][2];
  s16x4 vf0[4][2], vf1[4][2];

  ATTN_LOAD(0, kf0, vf0);
  int kt = 0;
  for (; kt + 2 <= N; kt += 2) {
    ATTN_LOAD((kt + 1) * 32, kf1, vf1);
    ATTN_COMP(kt * 32, kf0, vf0, false);        // kt <= N-2: never diagonal
    if (kt + 2 < N) ATTN_LOAD((kt + 2) * 32, kf0, vf0);
    ATTN_COMP((kt + 1) * 32, kf1, vf1, kt + 1 == N - 1);
  }
  if (kt < N) ATTN_COMP(kt * 32, kf0, vf0, true);  // odd N: last tile

  // epilogue: normalize, gate, residual -> x2 (bf16)
#pragma unroll
  for (int qt = 0; qt < 2; ++qt) {
    const float rinv = 1.f / lsum[qt];
    const int q = q0w + qt * 16 + lr;
#pragma unroll
    for (int dt = 0; dt < 4; ++dt) {
      const int colb = h * 64 + dt * 16 + lg * 4;
      const size_t idx2 = ((size_t)b * Tn + q) * Cn + colb;
      float4 xv = *(const float4*)(x + idx2);
      float4 gv = *(const float4*)(cm + b * 6144 + 2048 + colb);
      u16x4 ov;
      ov.x = f2bf(xv.x + gv.x * o[qt][dt][0] * rinv);
      ov.y = f2bf(xv.y + gv.y * o[qt][dt][1] * rinv);
      ov.z = f2bf(xv.z + gv.z * o[qt][dt][2] * rinv);
      ov.w = f2bf(xv.w + gv.w * o[qt][dt][3] * rinv);
      *(u16x4*)(x2 + idx2) = ov;
    }
  }
}

// ---------------- launch ----------------
extern "C" void kernel_launch(void* const* d_in, const int* in_sizes, int n_in,
                              void* d_out, int out_size, void* d_ws, size_t ws_size,
                              hipStream_t stream) {
  (void)in_sizes; (void)n_in; (void)out_size; (void)ws_size;
  const float* x = (const float*)d_in[0];
  const float* pe_cos = (const float*)d_in[1];
  const float* pe_sin = (const float*)d_in[2];
  const float* pe_scale = (const float*)d_in[3];
  const float* cc = (const float*)d_in[4];
  // d_in[5] = mask: causal, computed analytically
  const float* qkv_w = (const float*)d_in[6];
  const float* qkv_b = (const float*)d_in[7];
  const float* w1 = (const float*)d_in[8];
  const float* b1 = (const float*)d_in[9];
  const float* w2 = (const float*)d_in[10];
  const float* b2 = (const float*)d_in[11];
  const float* ada_w = (const float*)d_in[12];
  const float* ada_b = (const float*)d_in[13];
  float* out = (float*)d_out;
  char* ws = (char*)d_ws;

  unsigned short* qkvw_bf = (unsigned short*)(ws + 0);
  unsigned short* w1_bf = (unsigned short*)(ws + 6291456);
  unsigned short* w2_bf = (unsigned short*)(ws + 14680064);
  float* cm = (float*)(ws + 23068672);
  unsigned short* h1 = (unsigned short*)(ws + 23117824);   // reused as h2
  unsigned short* ff1b = (unsigned short*)(ws + 31506432);
  unsigned short* Qb = (unsigned short*)(ws + 56672256);
  unsigned short* Kb2 = (unsigned short*)(ws + 65060864);
  unsigned short* Vtb = (unsigned short*)(ws + 73449472);
  unsigned short* x2b = (unsigned short*)(ws + 81838080);  // bf16 (8 MB)
  // total ws use: < 98,615,296 bytes

  prep_kernel<<<12800, 256, 0, stream>>>(qkv_w, w1, w2, qkvw_bf, w1_bf, w2_bf,
                                         cc, ada_w, ada_b, cm);
  ln_mod<false><<<4096, 256, 0, stream>>>(x, cm, h1, 0, 1024);
  gemm_bt<3, 128, 32><<<dim3(24, 32), 256, 0, stream>>>(
      h1, qkvw_bf, qkv_b, nullptr, nullptr, nullptr, nullptr, 4096, 3072, 1024,
      pe_cos, pe_sin, pe_scale, Qb, Kb2, Vtb);
  attn_kernel<<<512, 256, 0, stream>>>(Qb, Kb2, Vtb, x, cm, x2b);
  ln_mod<true><<<4096, 256, 0, stream>>>(x2b, cm, h1, 3072, 4096);
  gemm_bt<1, 128, 64><<<dim3(32, 32), 256, 0, stream>>>(
      h1, w1_bf, b1, ff1b, nullptr, nullptr, nullptr, 4096, 4096, 1024,
      nullptr, nullptr, nullptr, nullptr, nullptr, nullptr);
  gemm_bt<2, 64, 64><<<dim3(8, 64), 256, 0, stream>>>(
      ff1b, w2_bf, b2, nullptr, out, x2b, cm, 4096, 1024, 4096,
      nullptr, nullptr, nullptr, nullptr, nullptr, nullptr);
}